// Round 16
// baseline (143.216 us; speedup 1.0000x reference)
//
#include <hip/hip_runtime.h>

#define EPS 1e-5f

constexpr int B   = 64;
constexpr int DIM = 384;
constexpr int PD  = 96;    // PDIM
constexpr int QKD = 16;    // QK
constexpr int N   = 1024;  // H*W
constexpr int OQ  = 128;   // 2*QK + PDIM
constexpr int Y2C = DIM - PD;  // 288
constexpr int VST = 68;    // V-tile LDS row stride (shorts); 96*68*2*4 = 52.2KB -> 3 blocks/CU
// 0.25 (softmax scale) * log2(e): folded into Q so QK^T lands in exp2-domain
#define QSCALE 0.3606737602222408f

typedef __attribute__((ext_vector_type(8))) short bf16x8;
typedef __attribute__((ext_vector_type(16))) float f32x16;

#define MFMA(a, b, c) __builtin_amdgcn_mfma_f32_32x32x16_bf16((a), (b), (c), 0, 0, 0)

// async global->LDS, 16B per lane; LDS dest is wave-uniform base + lane*16
#define GLOAD16(gsrc, ldst)                                                    \
    __builtin_amdgcn_global_load_lds(                                          \
        (const __attribute__((address_space(1))) void*)(gsrc),                 \
        (__attribute__((address_space(3))) void*)(ldst), 16, 0, 0)

__device__ __forceinline__ unsigned short f2bf(float f) {
    union { float f; unsigned u; } v; v.f = f;
    unsigned r = v.u + 0x7fffu + ((v.u >> 16) & 1u);
    return (unsigned short)(r >> 16);
}
__device__ __forceinline__ unsigned pack2(float a, float b) {
    return (unsigned)f2bf(a) | ((unsigned)f2bf(b) << 16);
}
// hardware packed f32->bf16 (RNE), 1 VALU op for 2 values
__device__ __forceinline__ unsigned cvtpk(float lo, float hi_) {
    unsigned r;
    asm("v_cvt_pk_bf16_f32 %0, %1, %2" : "=v"(r) : "v"(lo), "v"(hi_));
    return r;
}
__device__ __forceinline__ float max3f(float a, float b, float c) {
    return fmaxf(fmaxf(a, b), c);   // clang fuses to v_max3_f32
}
__device__ __forceinline__ f32x16 zero16() {
    f32x16 z;
#pragma unroll
    for (int i = 0; i < 16; i++) z[i] = 0.f;
    return z;
}

// ---------------- K1: fused pre-pass.
// blocks 0..511: GN partial sums, 8 blocks per batch (12 float4/thread,
//   fully unrolled, 4 accumulators -> loads pipelined, not serialized).
// blocks 512..1087: Wp conv.  blocks 1088..1135: Wq conv.
__global__ __launch_bounds__(256) void k_pre(const float* __restrict__ x,
                                             float* __restrict__ part,
                                             const float* __restrict__ pw,
                                             const float* __restrict__ pbnw,
                                             const float* __restrict__ pbnb,
                                             const float* __restrict__ pbnm,
                                             const float* __restrict__ pbnv,
                                             short* __restrict__ Wp,
                                             float* __restrict__ bias,
                                             const float* __restrict__ qw,
                                             const float* __restrict__ qbnw,
                                             const float* __restrict__ qbnb,
                                             const float* __restrict__ qbnm,
                                             const float* __restrict__ qbnv,
                                             short* __restrict__ Wq,
                                             float* __restrict__ qbias) {
    __shared__ float r1[4], r2[4];
    int gb = blockIdx.x;
    int tid = threadIdx.x;
    if (gb < 512) {                      // ---- GN partial sums: batch gb>>3, part gb&7
        int b = gb >> 3, p = gb & 7;
        const float4* xp = (const float4*)(x + (size_t)b * DIM * N) + p * 3072;
        float s1a = 0.f, s1b = 0.f, s1c = 0.f, s1d = 0.f;
        float s2a = 0.f, s2b = 0.f, s2c = 0.f, s2d = 0.f;
        #pragma unroll
        for (int i = 0; i < 12; i += 4) {
            float4 v0 = xp[tid + (i + 0) * 256];
            float4 v1 = xp[tid + (i + 1) * 256];
            float4 v2 = xp[tid + (i + 2) * 256];
            float4 v3 = xp[tid + (i + 3) * 256];
            s1a += v0.x + v0.y + v0.z + v0.w;
            s2a += v0.x * v0.x + v0.y * v0.y + v0.z * v0.z + v0.w * v0.w;
            s1b += v1.x + v1.y + v1.z + v1.w;
            s2b += v1.x * v1.x + v1.y * v1.y + v1.z * v1.z + v1.w * v1.w;
            s1c += v2.x + v2.y + v2.z + v2.w;
            s2c += v2.x * v2.x + v2.y * v2.y + v2.z * v2.z + v2.w * v2.w;
            s1d += v3.x + v3.y + v3.z + v3.w;
            s2d += v3.x * v3.x + v3.y * v3.y + v3.z * v3.z + v3.w * v3.w;
        }
        float s1 = (s1a + s1b) + (s1c + s1d);
        float s2 = (s2a + s2b) + (s2c + s2d);
        for (int o = 32; o > 0; o >>= 1) {
            s1 += __shfl_down(s1, o, 64);
            s2 += __shfl_down(s2, o, 64);
        }
        int wave = tid >> 6, lane = tid & 63;
        if (lane == 0) { r1[wave] = s1; r2[wave] = s2; }
        __syncthreads();
        if (tid == 0) {
            part[(b * 8 + p) * 2 + 0] = r1[0] + r1[1] + r1[2] + r1[3];
            part[(b * 8 + p) * 2 + 1] = r2[0] + r2[1] + r2[2] + r2[3];
        }
    } else if (gb < 512 + 576) {         // ---- Wp = bf16(proj_w * bn_inv)
        int idx = (gb - 512) * 256 + tid;
        int o = idx / DIM;
        float inv = pbnw[o] * rsqrtf(pbnv[o] + EPS);
        Wp[idx] = (short)f2bf(pw[idx] * inv);
        if (idx < DIM) bias[idx] = pbnb[idx] - pbnm[idx] * (pbnw[idx] * rsqrtf(pbnv[idx] + EPS));
    } else {                             // ---- Wq = bf16(qkv_w * bn_inv * qscale)
        int idx = (gb - 1088) * 256 + tid;
        int o = idx / PD;
        float inv = qbnw[o] * rsqrtf(qbnv[o] + EPS);
        float f = (o < QKD) ? QSCALE : 1.f;
        Wq[idx] = (short)f2bf(qw[idx] * inv * f);
        if (idx < OQ) {
            float invb = qbnw[idx] * rsqrtf(qbnv[idx] + EPS);
            float fb = (idx < QKD) ? QSCALE : 1.f;
            qbias[idx] = (qbnb[idx] - qbnm[idx] * invb) * fb;
        }
    }
}

// ---------------- K2: MFMA QKV GEMM with fused GN+transpose staging.
// [128 o] x [128 n], K=96 single-shot. mu/rsig reduced from the 16 partials
// at block start (LDS broadcast). B-operand built from x directly.
__global__ __launch_bounds__(256) void k_qkv(const float* __restrict__ x,
                                             const float* __restrict__ part,
                                             const float* __restrict__ gnw,
                                             const float* __restrict__ gnb,
                                             const short* __restrict__ Wq,
                                             const float* __restrict__ qbias,
                                             short* __restrict__ Qt,
                                             short* __restrict__ Kt,
                                             short* __restrict__ Vw) {
    alignas(16) __shared__ short Wl[128 * 104];
    alignas(16) __shared__ short Xl[128 * 104];
    __shared__ short t[32][132];
    __shared__ float qbl[OQ];
    __shared__ float pr[16];
    int b = blockIdx.x, nb = blockIdx.y;
    int tid = threadIdx.x, w = tid >> 6, l = tid & 63;
    int col = l & 31, hi = l >> 5;
    int wr = w >> 1, wc = w & 1;
    int n0 = nb * 128;

    if (tid < 16) pr[tid] = part[b * 16 + tid];
    if (tid >= 64 && tid < 64 + OQ) qbl[tid - 64] = qbias[tid - 64];
    #pragma unroll
    for (int it = 0; it < 6; it++) {
        int e = tid + 256 * it;          // 0..1535
        int row = e / 12, slot = e % 12;
        *(uint4*)&Wl[row * 104 + slot * 8] = *(const uint4*)(Wq + row * PD + slot * 8);
    }
    __syncthreads();
    float s1 = (pr[0] + pr[2]) + (pr[4] + pr[6]) + (pr[8] + pr[10]) + (pr[12] + pr[14]);
    float s2 = (pr[1] + pr[3]) + (pr[5] + pr[7]) + (pr[9] + pr[11]) + (pr[13] + pr[15]);
    float mu = s1 / (PD * N);
    float var = s2 / (PD * N) - mu * mu;
    float rsig = rsqrtf(var + EPS);

    const float* xb = x + (size_t)b * DIM * N + n0;
    for (int ct = 0; ct < 3; ct++) {
        int c0 = ct * 32;
        if (ct) __syncthreads();         // protect t reuse across chunks
        #pragma unroll
        for (int i = 0; i < 4; i++) {
            int e = tid + 256 * i;
            int c = e >> 5, q4 = e & 31;
            float4 v = *(const float4*)(xb + (size_t)(c0 + c) * N + q4 * 4);
            float s = rsig * gnw[c0 + c];
            float tt = gnb[c0 + c] - mu * s;
            uint2 d;
            d.x = pack2(s * v.x + tt, s * v.y + tt);
            d.y = pack2(s * v.z + tt, s * v.w + tt);
            *(uint2*)&t[c][q4 * 4] = d;
        }
        __syncthreads();
        #pragma unroll
        for (int i = 0; i < 8; i++) {
            int e = tid + 256 * i;
            int n = e >> 4, cp = e & 15;
            unsigned lo = (unsigned short)t[2 * cp][n];
            unsigned hi2 = (unsigned short)t[2 * cp + 1][n];
            *(unsigned*)&Xl[n * 104 + c0 + 2 * cp] = lo | (hi2 << 16);
        }
    }
    __syncthreads();

    f32x16 acc[2][2];
    acc[0][0] = zero16(); acc[0][1] = zero16();
    acc[1][0] = zero16(); acc[1][1] = zero16();
    #pragma unroll
    for (int ks = 0; ks < 6; ks++) {
        int ko = ks * 16 + hi * 8;
        int ra0 = wr * 64 + col, ra1 = ra0 + 32;
        int rb0 = wc * 64 + col, rb1 = rb0 + 32;
        bf16x8 a0 = *(const bf16x8*)&Wl[ra0 * 104 + ko];
        bf16x8 a1 = *(const bf16x8*)&Wl[ra1 * 104 + ko];
        bf16x8 b0 = *(const bf16x8*)&Xl[rb0 * 104 + ko];
        bf16x8 b1 = *(const bf16x8*)&Xl[rb1 * 104 + ko];
        acc[0][0] = MFMA(a0, b0, acc[0][0]);
        acc[0][1] = MFMA(a0, b1, acc[0][1]);
        acc[1][0] = MFMA(a1, b0, acc[1][0]);
        acc[1][1] = MFMA(a1, b1, acc[1][1]);
    }

    #pragma unroll
    for (int m = 0; m < 2; m++) {
        int o_base = wr * 64 + m * 32;
        #pragma unroll
        for (int nn = 0; nn < 2; nn++) {
            int n = n0 + wc * 64 + nn * 32 + col;
            f32x16 a = acc[m][nn];
            if (o_base == 0) {
                // o 0..15 -> Q, 16..31 -> K
                #pragma unroll
                for (int g = 0; g < 4; g++) {
                    int ofr = 8 * g + 4 * hi;   // frag-o base: 0,8,16,24 (+4hi)
                    float v0 = a[4 * g + 0] + qbl[ofr + 0];
                    float v1 = a[4 * g + 1] + qbl[ofr + 1];
                    float v2 = a[4 * g + 2] + qbl[ofr + 2];
                    float v3 = a[4 * g + 3] + qbl[ofr + 3];
                    uint2 d; d.x = pack2(v0, v1); d.y = pack2(v2, v3);
                    short* dst = (g < 2)
                        ? (Qt + ((size_t)b * N + n) * QKD + (ofr & 15))
                        : (Kt + ((size_t)b * N + n) * QKD + (ofr & 15));
                    *(uint2*)dst = d;
                }
            } else {
                int c0 = o_base - 32;          // 0, 32, 64
                short* vb = Vw + ((size_t)b * PD + c0) * N + n;
                #pragma unroll
                for (int r = 0; r < 16; r++) {
                    int cf = (r & 3) + 8 * (r >> 2) + 4 * hi;
                    vb[(size_t)cf * N] = (short)f2bf(a[r] + qbl[32 + c0 + cf]);
                }
            }
        }
    }
}

// ---------------------------------------- K3: MFMA flash attention, LDS-staged V
// grid (B, 8), 512 threads = 8 waves = 4 q-tiles x 2 key-splits (512 keys each).
// One softmax update per 64 keys. V staged via LDS double-buffer, T14
// issue-early/write-late. Row stride 68 shorts: LDS 52.2 KB -> 3 blocks/CU
// (was 72 -> 55.3 KB -> 2 blocks/CU); <=2-way bank aliasing (free).
__global__ __launch_bounds__(512, 2) void k_attn(const short* __restrict__ Qt,
                                                 const short* __restrict__ Kt,
                                                 const short* __restrict__ Vb,
                                                 short* __restrict__ y1t) {
    alignas(16) __shared__ char lds_raw[4 * 96 * VST * 2];  // 52224 B
    short* Vs = (short*)lds_raw;   // [split][buf][96*VST]
    float* combA_ = (float*)lds_raw;               // [4][64][49] = 50176 B
    float* combM_ = (float*)(lds_raw + 50176);     // [4][64]
    float* combL_ = (float*)(lds_raw + 51200);     // [4][64]

    int b = blockIdx.x;
    int tid = threadIdx.x;
    int split = tid >> 8;
    int s_tid = tid & 255;
    int w = tid >> 6, lane = tid & 63;
    int qgrp = w & 3;
    int col = lane & 31, hi = lane >> 5;
    int q0 = blockIdx.y * 128 + qgrp * 32;
    int kbeg = split * 512;

    const short* kbase = Kt + (size_t)b * N * QKD;
    const short* vbase = Vb + (size_t)b * PD * N;
    const bf16x8 qf = *(const bf16x8*)(Qt + ((size_t)b * N + q0 + col) * QKD + hi * 8);

    short* vs0 = Vs + (split * 2 + 0) * (96 * VST);
    short* vs1 = Vs + (split * 2 + 1) * (96 * VST);

    bf16x8 kf0 = *(const bf16x8*)(kbase + (size_t)(kbeg + col) * QKD + hi * 8);
    bf16x8 kf1 = *(const bf16x8*)(kbase + (size_t)(kbeg + 32 + col) * QKD + hi * 8);
    {
        int t0 = s_tid, t1 = s_tid + 256, t2i = s_tid + 512;
        uint4 g0 = *(const uint4*)(vbase + (size_t)(t0 >> 3) * N + kbeg + (t0 & 7) * 8);
        uint4 g1 = *(const uint4*)(vbase + (size_t)(t1 >> 3) * N + kbeg + (t1 & 7) * 8);
        uint4 g2 = *(const uint4*)(vbase + (size_t)(t2i >> 3) * N + kbeg + (t2i & 7) * 8);
        *(uint4*)(vs0 + (t0 >> 3) * VST + (t0 & 7) * 8) = g0;
        *(uint4*)(vs0 + (t1 >> 3) * VST + (t1 & 7) * 8) = g1;
        *(uint4*)(vs0 + (t2i >> 3) * VST + (t2i & 7) * 8) = g2;
    }
    __syncthreads();

    f32x16 acc0 = zero16(), acc1 = zero16(), acc2 = zero16();
    float m = -1e30f, lsum = 0.f;

    for (int it = 0; it < 8; it++) {
        int m0 = kbeg + it * 64;
        short* cur = (it & 1) ? vs1 : vs0;
        short* nxt = (it & 1) ? vs0 : vs1;
        bool more = (it < 7);
        int m0n = more ? m0 + 64 : m0;
        bf16x8 kf0n = *(const bf16x8*)(kbase + (size_t)(m0n + col) * QKD + hi * 8);
        bf16x8 kf1n = *(const bf16x8*)(kbase + (size_t)(m0n + 32 + col) * QKD + hi * 8);
        uint4 g0, g1, g2;
        if (more) {
            int t0 = s_tid, t1 = s_tid + 256, t2i = s_tid + 512;
            g0 = *(const uint4*)(vbase + (size_t)(t0 >> 3) * N + m0n + (t0 & 7) * 8);
            g1 = *(const uint4*)(vbase + (size_t)(t1 >> 3) * N + m0n + (t1 & 7) * 8);
            g2 = *(const uint4*)(vbase + (size_t)(t2i >> 3) * N + m0n + (t2i & 7) * 8);
        }

        f32x16 s0 = MFMA(kf0, qf, zero16());
        f32x16 s1 = MFMA(kf1, qf, zero16());
        float a0 = max3f(s0[0], s0[1], s0[2]),  a1 = max3f(s0[3], s0[4], s0[5]);
        float a2 = max3f(s0[6], s0[7], s0[8]),  a3 = max3f(s0[9], s0[10], s0[11]);
        float a4 = max3f(s0[12], s0[13], s0[14]);
        float cm0 = fmaxf(max3f(a0, a1, a2), max3f(a3, a4, s0[15]));
        float b0_ = max3f(s1[0], s1[1], s1[2]),  b1_ = max3f(s1[3], s1[4], s1[5]);
        float b2_ = max3f(s1[6], s1[7], s1[8]),  b3_ = max3f(s1[9], s1[10], s1[11]);
        float b4_ = max3f(s1[12], s1[13], s1[14]);
        float cm1 = fmaxf(max3f(b0_, b1_, b2_), max3f(b3_, b4_, s1[15]));
        float cm = fmaxf(cm0, cm1);
        cm = fmaxf(cm, __shfl_xor(cm, 32, 64));
        if (!__all(cm <= m + 8.f)) {       // defer-max (T13), once per 64 keys
            float mnew = fmaxf(m, cm);
            float corr = __builtin_amdgcn_exp2f(m - mnew);
            m = mnew;
            lsum *= corr;
            #pragma unroll
            for (int r = 0; r < 16; r++) { acc0[r] *= corr; acc1[r] *= corr; acc2[r] *= corr; }
        }
        float ps = 0.f;
        bf16x8 pbv[2][2];
        #pragma unroll
        for (int s32 = 0; s32 < 2; s32++) {
            const f32x16& s = s32 ? s1 : s0;
            unsigned pw[8];
            #pragma unroll
            for (int j = 0; j < 8; j++) {
                float p0 = __builtin_amdgcn_exp2f(s[2 * j] - m);
                float p1 = __builtin_amdgcn_exp2f(s[2 * j + 1] - m);
                ps += p0 + p1;
                pw[j] = cvtpk(p0, p1);
            }
            unsigned xw[8];
            #pragma unroll
            for (int j = 0; j < 8; j++) xw[j] = __shfl_xor(pw[j], 32, 64);
            union { unsigned u[4]; bf16x8 v; } pb0, pb1;
            if (hi == 0) {
                pb0.u[0] = pw[0]; pb0.u[1] = pw[1]; pb0.u[2] = xw[0]; pb0.u[3] = xw[1];
                pb1.u[0] = pw[4]; pb1.u[1] = pw[5]; pb1.u[2] = xw[4]; pb1.u[3] = xw[5];
            } else {
                pb0.u[0] = xw[2]; pb0.u[1] = xw[3]; pb0.u[2] = pw[2]; pb0.u[3] = pw[3];
                pb1.u[0] = xw[6]; pb1.u[1] = xw[7]; pb1.u[2] = pw[6]; pb1.u[3] = pw[7];
            }
            pbv[s32][0] = pb0.v;
            pbv[s32][1] = pb1.v;
        }
        ps += __shfl_xor(ps, 32, 64);
        lsum += ps;
        __builtin_amdgcn_s_setprio(1);
        #pragma unroll
        for (int s32 = 0; s32 < 2; s32++) {
            const short* vt32 = cur + s32 * 32 + hi * 8;
            bf16x8 pa = pbv[s32][0], pq = pbv[s32][1];
            bf16x8 va0 = *(const bf16x8*)(vt32 + col * VST);
            bf16x8 va1 = *(const bf16x8*)(vt32 + col * VST + 16);
            acc0 = MFMA(va0, pa, acc0);
            acc0 = MFMA(va1, pq, acc0);
            bf16x8 vb0 = *(const bf16x8*)(vt32 + (32 + col) * VST);
            bf16x8 vb1 = *(const bf16x8*)(vt32 + (32 + col) * VST + 16);
            acc1 = MFMA(vb0, pa, acc1);
            acc1 = MFMA(vb1, pq, acc1);
            bf16x8 vc0 = *(const bf16x8*)(vt32 + (64 + col) * VST);
            bf16x8 vc1 = *(const bf16x8*)(vt32 + (64 + col) * VST + 16);
            acc2 = MFMA(vc0, pa, acc2);
            acc2 = MFMA(vc1, pq, acc2);
        }
        __builtin_amdgcn_s_setprio(0);
        kf0 = kf0n; kf1 = kf1n;
        if (more) {
            int t0 = s_tid, t1 = s_tid + 256, t2i = s_tid + 512;
            *(uint4*)(nxt + (t0 >> 3) * VST + (t0 & 7) * 8) = g0;
            *(uint4*)(nxt + (t1 >> 3) * VST + (t1 & 7) * 8) = g1;
            *(uint4*)(nxt + (t2i >> 3) * VST + (t2i & 7) * 8) = g2;
            __syncthreads();
        }
    }

    __syncthreads();
    if (split == 1) {
        float* dst = combA_ + (qgrp * 64 + lane) * 49;
        #pragma unroll
        for (int r = 0; r < 16; r++) {
            dst[r] = acc0[r]; dst[16 + r] = acc1[r]; dst[32 + r] = acc2[r];
        }
        combM_[qgrp * 64 + lane] = m;
        combL_[qgrp * 64 + lane] = lsum;
    }
    __syncthreads();
    if (split == 0) {
        float m2 = combM_[qgrp * 64 + lane], l2 = combL_[qgrp * 64 + lane];
        float M  = fmaxf(m, m2);
        float c1 = __builtin_amdgcn_exp2f(m - M);
        float c2 = __builtin_amdgcn_exp2f(m2 - M);
        float inv = 1.f / (lsum * c1 + l2 * c2);
        const float* src = combA_ + (qgrp * 64 + lane) * 49;
        float f1 = c1 * inv, f2 = c2 * inv;
        short* yrow = y1t + ((size_t)b * N + q0 + col) * PD;
        #pragma unroll
        for (int cg = 0; cg < 3; cg++) {
            f32x16 a = (cg == 0) ? acc0 : ((cg == 1) ? acc1 : acc2);
            const float* sr = src + cg * 16;
            #pragma unroll
            for (int j = 0; j < 8; j++) {
                float v0 = a[2 * j] * f1 + sr[2 * j] * f2;
                float v1 = a[2 * j + 1] * f1 + sr[2 * j + 1] * f2;
                v0 = v0 / (1.f + __expf(-v0));   // silu
                v1 = v1 / (1.f + __expf(-v1));
                int c = cg * 32 + ((2 * j) & 3) + 8 * (j >> 1) + 4 * hi;
                *(unsigned*)(yrow + c) = pack2(v0, v1);
            }
        }
    }
}

// ---------------- K4: y2t[b][n][c-96] = bf16(silu(x[b][c][n])) (float4 reads)
__global__ __launch_bounds__(256) void k_trans(const float* __restrict__ x,
                                               short* __restrict__ y2t) {
    int b = blockIdx.x, ct = blockIdx.y, nt = blockIdx.z;
    int tid = threadIdx.x;
    __shared__ short t[32][132];
    int c0 = PD + ct * 32, n0 = nt * 128;
    const float* xb = x + ((size_t)b * DIM + c0) * N + n0;
    #pragma unroll
    for (int i = 0; i < 4; i++) {
        int e = tid + 256 * i;
        int c = e >> 5, q4 = e & 31;
        float4 v = *(const float4*)(xb + (size_t)c * N + q4 * 4);
        float s0 = v.x / (1.f + __expf(-v.x));
        float s1 = v.y / (1.f + __expf(-v.y));
        float s2 = v.z / (1.f + __expf(-v.z));
        float s3 = v.w / (1.f + __expf(-v.w));
        uint2 d;
        d.x = pack2(s0, s1);
        d.y = pack2(s2, s3);
        *(uint2*)&t[c][q4 * 4] = d;
    }
    __syncthreads();
    #pragma unroll
    for (int i = 0; i < 8; i++) {
        int e = tid + 256 * i;
        int n = e >> 4, cp = e & 15;
        unsigned lo = (unsigned short)t[2 * cp][n];
        unsigned hi = (unsigned short)t[2 * cp + 1][n];
        *(unsigned*)(y2t + ((size_t)b * N + n0 + n) * Y2C + ct * 32 + 2 * cp) = lo | (hi << 16);
    }
}

// ---------------- K5: out = W' @ [y1t; y2t] + bias
// LDS-staged MFMA GEMM (m97 structure): 128o x 128n tile, BK=32, 4 waves.
__global__ __launch_bounds__(256) void k_proj(const short* __restrict__ Wp,
                                              const short* __restrict__ y1t,
                                              const short* __restrict__ y2t,
                                              const float* __restrict__ bias,
                                              float* __restrict__ out) {
    __shared__ short Asl[128 * 32];
    __shared__ short Bsl[128 * 32];
    int b = blockIdx.x, ob = blockIdx.y, nb = blockIdx.z;
    int tid = threadIdx.x, w = tid >> 6, l = tid & 63;
    int col = l & 31, hi = l >> 5;
    int wr = w >> 1, wc = w & 1;
    int o0 = ob * 128, n0 = nb * 128;
    size_t bn = (size_t)b * N + n0;

    f32x16 acc[2][2];
    acc[0][0] = zero16(); acc[0][1] = zero16();
    acc[1][0] = zero16(); acc[1][1] = zero16();

    int srow = (l >> 2);        // 0..15 within a 16-row issue
    int sslotbase = (l & 3);    // 16B slot within 64B row

    for (int step = 0; step < 12; step++) {
        int k0 = step * 32;
        const short* ysrc;
        int ystride, kq;
        if (k0 < PD) { ysrc = y1t; ystride = PD;  kq = k0; }
        else         { ysrc = y2t; ystride = Y2C; kq = k0 - PD; }
        #pragma unroll
        for (int i = 0; i < 2; i++) {
            int row = w * 32 + i * 16 + srow;
            int sl = sslotbase ^ (row & 3);
            GLOAD16(Wp + (size_t)(o0 + row) * DIM + k0 + sl * 8,
                    &Asl[(w * 32 + i * 16) * 32]);
            GLOAD16(ysrc + (bn + row) * ystride + kq + sl * 8,
                    &Bsl[(w * 32 + i * 16) * 32]);
        }
        __syncthreads();
        #pragma unroll
        for (int kh = 0; kh < 2; kh++) {
            int bxor = ((kh << 5) + (hi << 4));
            int ra0 = wr * 64 + col,      ra1 = ra0 + 32;
            int rb0 = wc * 64 + col,      rb1 = rb0 + 32;
            bf16x8 a0 = *(const bf16x8*)&Asl[ra0 * 32 + ((bxor ^ ((ra0 & 3) << 4)) >> 1)];
            bf16x8 a1 = *(const bf16x8*)&Asl[ra1 * 32 + ((bxor ^ ((ra1 & 3) << 4)) >> 1)];
            bf16x8 b0 = *(const bf16x8*)&Bsl[rb0 * 32 + ((bxor ^ ((rb0 & 3) << 4)) >> 1)];
            bf16x8 b1 = *(const bf16x8*)&Bsl[rb1 * 32 + ((bxor ^ ((rb1 & 3) << 4)) >> 1)];
            acc[0][0] = MFMA(a0, b0, acc[0][0]);
            acc[0][1] = MFMA(a0, b1, acc[0][1]);
            acc[1][0] = MFMA(a1, b0, acc[1][0]);
            acc[1][1] = MFMA(a1, b1, acc[1][1]);
        }
        __syncthreads();
    }
    #pragma unroll
    for (int m = 0; m < 2; m++) {
        #pragma unroll
        for (int n = 0; n < 2; n++) {
            #pragma unroll
            for (int r = 0; r < 16; r++) {
                int o = o0 + wr * 64 + m * 32 + (r & 3) + 8 * (r >> 2) + 4 * hi;
                out[((size_t)b * DIM + o) * N + n0 + wc * 64 + n * 32 + col] =
                    acc[m][n][r] + bias[o];
            }
        }
    }
}

// -----------------------------------------------------------------------------
// ws layout (~50.7 MB): y2t (37.75 MB) aliases [Qt,Kt,Vw]+tail (dead after
// k_attn; k_trans runs after k_attn on the same stream; rewritten every call).
extern "C" void kernel_launch(void* const* d_in, const int* in_sizes, int n_in,
                              void* d_out, int out_size, void* d_ws, size_t ws_size,
                              hipStream_t stream) {
    const float* x    = (const float*)d_in[0];
    const float* gnw  = (const float*)d_in[1];
    const float* gnb  = (const float*)d_in[2];
    const float* qkvw = (const float*)d_in[3];
    const float* qbnw = (const float*)d_in[4];
    const float* qbnb = (const float*)d_in[5];
    const float* qbnm = (const float*)d_in[6];
    const float* qbnv = (const float*)d_in[7];
    const float* pw   = (const float*)d_in[8];
    const float* pbnw = (const float*)d_in[9];
    const float* pbnb = (const float*)d_in[10];
    const float* pbnm = (const float*)d_in[11];
    const float* pbnv = (const float*)d_in[12];
    float* out = (float*)d_out;

    char* p = (char*)d_ws;
    float* part  = (float*)p;  p += 4096;                      // 64*8*2 floats
    short* Wp    = (short*)p;  p += (size_t)DIM * DIM * 2;     // 288 KB
    float* bias  = (float*)p;  p += 1536;                      // DIM*4
    short* Wq    = (short*)p;  p += (size_t)OQ * PD * 2;       // 24 KB
    float* qbias = (float*)p;  p += 512;                       // OQ*4
    short* y1t   = (short*)p;  p += (size_t)B * N * PD * 2;    // 12.6 MB
    short* Qt    = (short*)p;                                  // 2 MB   (dead after attn)
    short* Kt    = Qt + (size_t)B * N * QKD;                   // 2 MB   (dead after attn)
    short* Vw    = Kt + (size_t)B * N * QKD;                   // 12.6 MB(dead after attn)
    short* y2t   = Qt;                                         // 37.75 MB alias

    k_pre<<<1136, 256, 0, stream>>>(x, part, pw, pbnw, pbnb, pbnm, pbnv, Wp, bias,
                                    qkvw, qbnw, qbnb, qbnm, qbnv, Wq, qbias);
    k_qkv<<<dim3(B, 8), 256, 0, stream>>>(x, part, gnw, gnb, Wq, qbias, Qt, Kt, Vw);
    k_attn<<<dim3(B, 8), 512, 0, stream>>>(Qt, Kt, Vw, y1t);
    k_trans<<<dim3(B, 9, 8), 256, 0, stream>>>(x, y2t);
    k_proj<<<dim3(B, 3, 8), 256, 0, stream>>>(Wp, y1t, y2t, bias, out);
}

// Round 17
// 108.309 us; speedup vs baseline: 1.3223x; 1.3223x over previous
//
#include <hip/hip_runtime.h>

#define EPS 1e-5f

constexpr int B   = 64;
constexpr int DIM = 384;
constexpr int PD  = 96;    // PDIM
constexpr int QKD = 16;    // QK
constexpr int N   = 1024;  // H*W
constexpr int OQ  = 128;   // 2*QK + PDIM
constexpr int Y2C = DIM - PD;  // 288
constexpr int VST = 72;    // V-tile LDS row stride (shorts); 144B = 16B-aligned rows
// 0.25 (softmax scale) * log2(e): folded into Q so QK^T lands in exp2-domain
#define QSCALE 0.3606737602222408f

typedef __attribute__((ext_vector_type(8))) short bf16x8;
typedef __attribute__((ext_vector_type(16))) float f32x16;

#define MFMA(a, b, c) __builtin_amdgcn_mfma_f32_32x32x16_bf16((a), (b), (c), 0, 0, 0)

// async global->LDS, 16B per lane; LDS dest is wave-uniform base + lane*16
#define GLOAD16(gsrc, ldst)                                                    \
    __builtin_amdgcn_global_load_lds(                                          \
        (const __attribute__((address_space(1))) void*)(gsrc),                 \
        (__attribute__((address_space(3))) void*)(ldst), 16, 0, 0)

__device__ __forceinline__ unsigned short f2bf(float f) {
    union { float f; unsigned u; } v; v.f = f;
    unsigned r = v.u + 0x7fffu + ((v.u >> 16) & 1u);
    return (unsigned short)(r >> 16);
}
__device__ __forceinline__ unsigned pack2(float a, float b) {
    return (unsigned)f2bf(a) | ((unsigned)f2bf(b) << 16);
}
// hardware packed f32->bf16 (RNE), 1 VALU op for 2 values
__device__ __forceinline__ unsigned cvtpk(float lo, float hi_) {
    unsigned r;
    asm("v_cvt_pk_bf16_f32 %0, %1, %2" : "=v"(r) : "v"(lo), "v"(hi_));
    return r;
}
__device__ __forceinline__ float max3f(float a, float b, float c) {
    return fmaxf(fmaxf(a, b), c);   // clang fuses to v_max3_f32
}
__device__ __forceinline__ f32x16 zero16() {
    f32x16 z;
#pragma unroll
    for (int i = 0; i < 16; i++) z[i] = 0.f;
    return z;
}

// ---------------- K1: fused pre-pass.
// blocks 0..511: GN partial sums, 8 blocks per batch (12 float4/thread,
//   fully unrolled, 4 accumulators -> loads pipelined, not serialized).
// blocks 512..1087: Wp conv.  blocks 1088..1135: Wq conv.
__global__ __launch_bounds__(256) void k_pre(const float* __restrict__ x,
                                             float* __restrict__ part,
                                             const float* __restrict__ pw,
                                             const float* __restrict__ pbnw,
                                             const float* __restrict__ pbnb,
                                             const float* __restrict__ pbnm,
                                             const float* __restrict__ pbnv,
                                             short* __restrict__ Wp,
                                             float* __restrict__ bias,
                                             const float* __restrict__ qw,
                                             const float* __restrict__ qbnw,
                                             const float* __restrict__ qbnb,
                                             const float* __restrict__ qbnm,
                                             const float* __restrict__ qbnv,
                                             short* __restrict__ Wq,
                                             float* __restrict__ qbias) {
    __shared__ float r1[4], r2[4];
    int gb = blockIdx.x;
    int tid = threadIdx.x;
    if (gb < 512) {                      // ---- GN partial sums: batch gb>>3, part gb&7
        int b = gb >> 3, p = gb & 7;
        const float4* xp = (const float4*)(x + (size_t)b * DIM * N) + p * 3072;
        float s1a = 0.f, s1b = 0.f, s1c = 0.f, s1d = 0.f;
        float s2a = 0.f, s2b = 0.f, s2c = 0.f, s2d = 0.f;
        #pragma unroll
        for (int i = 0; i < 12; i += 4) {
            float4 v0 = xp[tid + (i + 0) * 256];
            float4 v1 = xp[tid + (i + 1) * 256];
            float4 v2 = xp[tid + (i + 2) * 256];
            float4 v3 = xp[tid + (i + 3) * 256];
            s1a += v0.x + v0.y + v0.z + v0.w;
            s2a += v0.x * v0.x + v0.y * v0.y + v0.z * v0.z + v0.w * v0.w;
            s1b += v1.x + v1.y + v1.z + v1.w;
            s2b += v1.x * v1.x + v1.y * v1.y + v1.z * v1.z + v1.w * v1.w;
            s1c += v2.x + v2.y + v2.z + v2.w;
            s2c += v2.x * v2.x + v2.y * v2.y + v2.z * v2.z + v2.w * v2.w;
            s1d += v3.x + v3.y + v3.z + v3.w;
            s2d += v3.x * v3.x + v3.y * v3.y + v3.z * v3.z + v3.w * v3.w;
        }
        float s1 = (s1a + s1b) + (s1c + s1d);
        float s2 = (s2a + s2b) + (s2c + s2d);
        for (int o = 32; o > 0; o >>= 1) {
            s1 += __shfl_down(s1, o, 64);
            s2 += __shfl_down(s2, o, 64);
        }
        int wave = tid >> 6, lane = tid & 63;
        if (lane == 0) { r1[wave] = s1; r2[wave] = s2; }
        __syncthreads();
        if (tid == 0) {
            part[(b * 8 + p) * 2 + 0] = r1[0] + r1[1] + r1[2] + r1[3];
            part[(b * 8 + p) * 2 + 1] = r2[0] + r2[1] + r2[2] + r2[3];
        }
    } else if (gb < 512 + 576) {         // ---- Wp = bf16(proj_w * bn_inv)
        int idx = (gb - 512) * 256 + tid;
        int o = idx / DIM;
        float inv = pbnw[o] * rsqrtf(pbnv[o] + EPS);
        Wp[idx] = (short)f2bf(pw[idx] * inv);
        if (idx < DIM) bias[idx] = pbnb[idx] - pbnm[idx] * (pbnw[idx] * rsqrtf(pbnv[idx] + EPS));
    } else {                             // ---- Wq = bf16(qkv_w * bn_inv * qscale)
        int idx = (gb - 1088) * 256 + tid;
        int o = idx / PD;
        float inv = qbnw[o] * rsqrtf(qbnv[o] + EPS);
        float f = (o < QKD) ? QSCALE : 1.f;
        Wq[idx] = (short)f2bf(qw[idx] * inv * f);
        if (idx < OQ) {
            float invb = qbnw[idx] * rsqrtf(qbnv[idx] + EPS);
            float fb = (idx < QKD) ? QSCALE : 1.f;
            qbias[idx] = (qbnb[idx] - qbnm[idx] * invb) * fb;
        }
    }
}

// ---------------- K2: MFMA QKV GEMM with fused GN+transpose staging.
// [128 o] x [128 n], K=96 single-shot. mu/rsig reduced from the 16 partials
// at block start (LDS broadcast). B-operand built from x directly.
__global__ __launch_bounds__(256) void k_qkv(const float* __restrict__ x,
                                             const float* __restrict__ part,
                                             const float* __restrict__ gnw,
                                             const float* __restrict__ gnb,
                                             const short* __restrict__ Wq,
                                             const float* __restrict__ qbias,
                                             short* __restrict__ Qt,
                                             short* __restrict__ Kt,
                                             short* __restrict__ Vw) {
    alignas(16) __shared__ short Wl[128 * 104];
    alignas(16) __shared__ short Xl[128 * 104];
    __shared__ short t[32][132];
    __shared__ float qbl[OQ];
    __shared__ float pr[16];
    int b = blockIdx.x, nb = blockIdx.y;
    int tid = threadIdx.x, w = tid >> 6, l = tid & 63;
    int col = l & 31, hi = l >> 5;
    int wr = w >> 1, wc = w & 1;
    int n0 = nb * 128;

    if (tid < 16) pr[tid] = part[b * 16 + tid];
    if (tid >= 64 && tid < 64 + OQ) qbl[tid - 64] = qbias[tid - 64];
    #pragma unroll
    for (int it = 0; it < 6; it++) {
        int e = tid + 256 * it;          // 0..1535
        int row = e / 12, slot = e % 12;
        *(uint4*)&Wl[row * 104 + slot * 8] = *(const uint4*)(Wq + row * PD + slot * 8);
    }
    __syncthreads();
    float s1 = (pr[0] + pr[2]) + (pr[4] + pr[6]) + (pr[8] + pr[10]) + (pr[12] + pr[14]);
    float s2 = (pr[1] + pr[3]) + (pr[5] + pr[7]) + (pr[9] + pr[11]) + (pr[13] + pr[15]);
    float mu = s1 / (PD * N);
    float var = s2 / (PD * N) - mu * mu;
    float rsig = rsqrtf(var + EPS);

    const float* xb = x + (size_t)b * DIM * N + n0;
    for (int ct = 0; ct < 3; ct++) {
        int c0 = ct * 32;
        if (ct) __syncthreads();         // protect t reuse across chunks
        #pragma unroll
        for (int i = 0; i < 4; i++) {
            int e = tid + 256 * i;
            int c = e >> 5, q4 = e & 31;
            float4 v = *(const float4*)(xb + (size_t)(c0 + c) * N + q4 * 4);
            float s = rsig * gnw[c0 + c];
            float tt = gnb[c0 + c] - mu * s;
            uint2 d;
            d.x = pack2(s * v.x + tt, s * v.y + tt);
            d.y = pack2(s * v.z + tt, s * v.w + tt);
            *(uint2*)&t[c][q4 * 4] = d;
        }
        __syncthreads();
        #pragma unroll
        for (int i = 0; i < 8; i++) {
            int e = tid + 256 * i;
            int n = e >> 4, cp = e & 15;
            unsigned lo = (unsigned short)t[2 * cp][n];
            unsigned hi2 = (unsigned short)t[2 * cp + 1][n];
            *(unsigned*)&Xl[n * 104 + c0 + 2 * cp] = lo | (hi2 << 16);
        }
    }
    __syncthreads();

    f32x16 acc[2][2];
    acc[0][0] = zero16(); acc[0][1] = zero16();
    acc[1][0] = zero16(); acc[1][1] = zero16();
    #pragma unroll
    for (int ks = 0; ks < 6; ks++) {
        int ko = ks * 16 + hi * 8;
        int ra0 = wr * 64 + col, ra1 = ra0 + 32;
        int rb0 = wc * 64 + col, rb1 = rb0 + 32;
        bf16x8 a0 = *(const bf16x8*)&Wl[ra0 * 104 + ko];
        bf16x8 a1 = *(const bf16x8*)&Wl[ra1 * 104 + ko];
        bf16x8 b0 = *(const bf16x8*)&Xl[rb0 * 104 + ko];
        bf16x8 b1 = *(const bf16x8*)&Xl[rb1 * 104 + ko];
        acc[0][0] = MFMA(a0, b0, acc[0][0]);
        acc[0][1] = MFMA(a0, b1, acc[0][1]);
        acc[1][0] = MFMA(a1, b0, acc[1][0]);
        acc[1][1] = MFMA(a1, b1, acc[1][1]);
    }

    #pragma unroll
    for (int m = 0; m < 2; m++) {
        int o_base = wr * 64 + m * 32;
        #pragma unroll
        for (int nn = 0; nn < 2; nn++) {
            int n = n0 + wc * 64 + nn * 32 + col;
            f32x16 a = acc[m][nn];
            if (o_base == 0) {
                // o 0..15 -> Q, 16..31 -> K
                #pragma unroll
                for (int g = 0; g < 4; g++) {
                    int ofr = 8 * g + 4 * hi;   // frag-o base: 0,8,16,24 (+4hi)
                    float v0 = a[4 * g + 0] + qbl[ofr + 0];
                    float v1 = a[4 * g + 1] + qbl[ofr + 1];
                    float v2 = a[4 * g + 2] + qbl[ofr + 2];
                    float v3 = a[4 * g + 3] + qbl[ofr + 3];
                    uint2 d; d.x = pack2(v0, v1); d.y = pack2(v2, v3);
                    short* dst = (g < 2)
                        ? (Qt + ((size_t)b * N + n) * QKD + (ofr & 15))
                        : (Kt + ((size_t)b * N + n) * QKD + (ofr & 15));
                    *(uint2*)dst = d;
                }
            } else {
                int c0 = o_base - 32;          // 0, 32, 64
                short* vb = Vw + ((size_t)b * PD + c0) * N + n;
                #pragma unroll
                for (int r = 0; r < 16; r++) {
                    int cf = (r & 3) + 8 * (r >> 2) + 4 * hi;
                    vb[(size_t)cf * N] = (short)f2bf(a[r] + qbl[32 + c0 + cf]);
                }
            }
        }
    }
}

// ---------------------------------------- K3: MFMA flash attention, LDS-staged V
// grid (B, 8), 512 threads = 8 waves = 4 q-tiles x 2 key-splits (512 keys each).
// One softmax update per 64 keys (combined max, single defer-max, exp against
// final m). V staged via LDS double-buffer, T14 issue-early/write-late.
// VST=72 (144B rows): 16B-aligned b128 access (VST=68 broke alignment, 2x cost).
__global__ __launch_bounds__(512, 2) void k_attn(const short* __restrict__ Qt,
                                                 const short* __restrict__ Kt,
                                                 const short* __restrict__ Vb,
                                                 short* __restrict__ y1t) {
    alignas(16) __shared__ char lds_raw[4 * 96 * VST * 2];  // 55296 B
    short* Vs = (short*)lds_raw;   // [split][buf][96*VST]
    float* combA_ = (float*)lds_raw;               // [4][64][49] = 50176 B
    float* combM_ = (float*)(lds_raw + 50176);     // [4][64]
    float* combL_ = (float*)(lds_raw + 51200);     // [4][64]

    int b = blockIdx.x;
    int tid = threadIdx.x;
    int split = tid >> 8;
    int s_tid = tid & 255;
    int w = tid >> 6, lane = tid & 63;
    int qgrp = w & 3;
    int col = lane & 31, hi = lane >> 5;
    int q0 = blockIdx.y * 128 + qgrp * 32;
    int kbeg = split * 512;

    const short* kbase = Kt + (size_t)b * N * QKD;
    const short* vbase = Vb + (size_t)b * PD * N;
    const bf16x8 qf = *(const bf16x8*)(Qt + ((size_t)b * N + q0 + col) * QKD + hi * 8);

    short* vs0 = Vs + (split * 2 + 0) * (96 * VST);
    short* vs1 = Vs + (split * 2 + 1) * (96 * VST);

    bf16x8 kf0 = *(const bf16x8*)(kbase + (size_t)(kbeg + col) * QKD + hi * 8);
    bf16x8 kf1 = *(const bf16x8*)(kbase + (size_t)(kbeg + 32 + col) * QKD + hi * 8);
    {
        int t0 = s_tid, t1 = s_tid + 256, t2i = s_tid + 512;
        uint4 g0 = *(const uint4*)(vbase + (size_t)(t0 >> 3) * N + kbeg + (t0 & 7) * 8);
        uint4 g1 = *(const uint4*)(vbase + (size_t)(t1 >> 3) * N + kbeg + (t1 & 7) * 8);
        uint4 g2 = *(const uint4*)(vbase + (size_t)(t2i >> 3) * N + kbeg + (t2i & 7) * 8);
        *(uint4*)(vs0 + (t0 >> 3) * VST + (t0 & 7) * 8) = g0;
        *(uint4*)(vs0 + (t1 >> 3) * VST + (t1 & 7) * 8) = g1;
        *(uint4*)(vs0 + (t2i >> 3) * VST + (t2i & 7) * 8) = g2;
    }
    __syncthreads();

    f32x16 acc0 = zero16(), acc1 = zero16(), acc2 = zero16();
    float m = -1e30f, lsum = 0.f;

    for (int it = 0; it < 8; it++) {
        int m0 = kbeg + it * 64;
        short* cur = (it & 1) ? vs1 : vs0;
        short* nxt = (it & 1) ? vs0 : vs1;
        bool more = (it < 7);
        int m0n = more ? m0 + 64 : m0;
        bf16x8 kf0n = *(const bf16x8*)(kbase + (size_t)(m0n + col) * QKD + hi * 8);
        bf16x8 kf1n = *(const bf16x8*)(kbase + (size_t)(m0n + 32 + col) * QKD + hi * 8);
        uint4 g0, g1, g2;
        if (more) {
            int t0 = s_tid, t1 = s_tid + 256, t2i = s_tid + 512;
            g0 = *(const uint4*)(vbase + (size_t)(t0 >> 3) * N + m0n + (t0 & 7) * 8);
            g1 = *(const uint4*)(vbase + (size_t)(t1 >> 3) * N + m0n + (t1 & 7) * 8);
            g2 = *(const uint4*)(vbase + (size_t)(t2i >> 3) * N + m0n + (t2i & 7) * 8);
        }

        f32x16 s0 = MFMA(kf0, qf, zero16());
        f32x16 s1 = MFMA(kf1, qf, zero16());
        float a0 = max3f(s0[0], s0[1], s0[2]),  a1 = max3f(s0[3], s0[4], s0[5]);
        float a2 = max3f(s0[6], s0[7], s0[8]),  a3 = max3f(s0[9], s0[10], s0[11]);
        float a4 = max3f(s0[12], s0[13], s0[14]);
        float cm0 = fmaxf(max3f(a0, a1, a2), max3f(a3, a4, s0[15]));
        float b0_ = max3f(s1[0], s1[1], s1[2]),  b1_ = max3f(s1[3], s1[4], s1[5]);
        float b2_ = max3f(s1[6], s1[7], s1[8]),  b3_ = max3f(s1[9], s1[10], s1[11]);
        float b4_ = max3f(s1[12], s1[13], s1[14]);
        float cm1 = fmaxf(max3f(b0_, b1_, b2_), max3f(b3_, b4_, s1[15]));
        float cm = fmaxf(cm0, cm1);
        cm = fmaxf(cm, __shfl_xor(cm, 32, 64));
        if (!__all(cm <= m + 8.f)) {       // defer-max (T13), once per 64 keys
            float mnew = fmaxf(m, cm);
            float corr = __builtin_amdgcn_exp2f(m - mnew);
            m = mnew;
            lsum *= corr;
            #pragma unroll
            for (int r = 0; r < 16; r++) { acc0[r] *= corr; acc1[r] *= corr; acc2[r] *= corr; }
        }
        float ps = 0.f;
        bf16x8 pbv[2][2];
        #pragma unroll
        for (int s32 = 0; s32 < 2; s32++) {
            const f32x16& s = s32 ? s1 : s0;
            unsigned pw[8];
            #pragma unroll
            for (int j = 0; j < 8; j++) {
                float p0 = __builtin_amdgcn_exp2f(s[2 * j] - m);
                float p1 = __builtin_amdgcn_exp2f(s[2 * j + 1] - m);
                ps += p0 + p1;
                pw[j] = cvtpk(p0, p1);
            }
            unsigned xw[8];
            #pragma unroll
            for (int j = 0; j < 8; j++) xw[j] = __shfl_xor(pw[j], 32, 64);
            union { unsigned u[4]; bf16x8 v; } pb0, pb1;
            if (hi == 0) {
                pb0.u[0] = pw[0]; pb0.u[1] = pw[1]; pb0.u[2] = xw[0]; pb0.u[3] = xw[1];
                pb1.u[0] = pw[4]; pb1.u[1] = pw[5]; pb1.u[2] = xw[4]; pb1.u[3] = xw[5];
            } else {
                pb0.u[0] = xw[2]; pb0.u[1] = xw[3]; pb0.u[2] = pw[2]; pb0.u[3] = pw[3];
                pb1.u[0] = xw[6]; pb1.u[1] = xw[7]; pb1.u[2] = pw[6]; pb1.u[3] = pw[7];
            }
            pbv[s32][0] = pb0.v;
            pbv[s32][1] = pb1.v;
        }
        ps += __shfl_xor(ps, 32, 64);
        lsum += ps;
        __builtin_amdgcn_s_setprio(1);
        #pragma unroll
        for (int s32 = 0; s32 < 2; s32++) {
            const short* vt32 = cur + s32 * 32 + hi * 8;
            bf16x8 pa = pbv[s32][0], pq = pbv[s32][1];
            bf16x8 va0 = *(const bf16x8*)(vt32 + col * VST);
            bf16x8 va1 = *(const bf16x8*)(vt32 + col * VST + 16);
            acc0 = MFMA(va0, pa, acc0);
            acc0 = MFMA(va1, pq, acc0);
            bf16x8 vb0 = *(const bf16x8*)(vt32 + (32 + col) * VST);
            bf16x8 vb1 = *(const bf16x8*)(vt32 + (32 + col) * VST + 16);
            acc1 = MFMA(vb0, pa, acc1);
            acc1 = MFMA(vb1, pq, acc1);
            bf16x8 vc0 = *(const bf16x8*)(vt32 + (64 + col) * VST);
            bf16x8 vc1 = *(const bf16x8*)(vt32 + (64 + col) * VST + 16);
            acc2 = MFMA(vc0, pa, acc2);
            acc2 = MFMA(vc1, pq, acc2);
        }
        __builtin_amdgcn_s_setprio(0);
        kf0 = kf0n; kf1 = kf1n;
        if (more) {
            int t0 = s_tid, t1 = s_tid + 256, t2i = s_tid + 512;
            *(uint4*)(nxt + (t0 >> 3) * VST + (t0 & 7) * 8) = g0;
            *(uint4*)(nxt + (t1 >> 3) * VST + (t1 & 7) * 8) = g1;
            *(uint4*)(nxt + (t2i >> 3) * VST + (t2i & 7) * 8) = g2;
            __syncthreads();
        }
    }

    __syncthreads();
    if (split == 1) {
        float* dst = combA_ + (qgrp * 64 + lane) * 49;
        #pragma unroll
        for (int r = 0; r < 16; r++) {
            dst[r] = acc0[r]; dst[16 + r] = acc1[r]; dst[32 + r] = acc2[r];
        }
        combM_[qgrp * 64 + lane] = m;
        combL_[qgrp * 64 + lane] = lsum;
    }
    __syncthreads();
    if (split == 0) {
        float m2 = combM_[qgrp * 64 + lane], l2 = combL_[qgrp * 64 + lane];
        float M  = fmaxf(m, m2);
        float c1 = __builtin_amdgcn_exp2f(m - M);
        float c2 = __builtin_amdgcn_exp2f(m2 - M);
        float inv = 1.f / (lsum * c1 + l2 * c2);
        const float* src = combA_ + (qgrp * 64 + lane) * 49;
        float f1 = c1 * inv, f2 = c2 * inv;
        short* yrow = y1t + ((size_t)b * N + q0 + col) * PD;
        #pragma unroll
        for (int cg = 0; cg < 3; cg++) {
            f32x16 a = (cg == 0) ? acc0 : ((cg == 1) ? acc1 : acc2);
            const float* sr = src + cg * 16;
            #pragma unroll
            for (int j = 0; j < 8; j++) {
                float v0 = a[2 * j] * f1 + sr[2 * j] * f2;
                float v1 = a[2 * j + 1] * f1 + sr[2 * j + 1] * f2;
                v0 = v0 / (1.f + __expf(-v0));   // silu
                v1 = v1 / (1.f + __expf(-v1));
                int c = cg * 32 + ((2 * j) & 3) + 8 * (j >> 1) + 4 * hi;
                *(unsigned*)(yrow + c) = pack2(v0, v1);
            }
        }
    }
}

// ---------------- K4: y2t[b][n][c-96] = bf16(silu(x[b][c][n])) (float4 reads)
__global__ __launch_bounds__(256) void k_trans(const float* __restrict__ x,
                                               short* __restrict__ y2t) {
    int b = blockIdx.x, ct = blockIdx.y, nt = blockIdx.z;
    int tid = threadIdx.x;
    __shared__ short t[32][132];
    int c0 = PD + ct * 32, n0 = nt * 128;
    const float* xb = x + ((size_t)b * DIM + c0) * N + n0;
    #pragma unroll
    for (int i = 0; i < 4; i++) {
        int e = tid + 256 * i;
        int c = e >> 5, q4 = e & 31;
        float4 v = *(const float4*)(xb + (size_t)c * N + q4 * 4);
        float s0 = v.x / (1.f + __expf(-v.x));
        float s1 = v.y / (1.f + __expf(-v.y));
        float s2 = v.z / (1.f + __expf(-v.z));
        float s3 = v.w / (1.f + __expf(-v.w));
        uint2 d;
        d.x = pack2(s0, s1);
        d.y = pack2(s2, s3);
        *(uint2*)&t[c][q4 * 4] = d;
    }
    __syncthreads();
    #pragma unroll
    for (int i = 0; i < 8; i++) {
        int e = tid + 256 * i;
        int n = e >> 4, cp = e & 15;
        unsigned lo = (unsigned short)t[2 * cp][n];
        unsigned hi = (unsigned short)t[2 * cp + 1][n];
        *(unsigned*)(y2t + ((size_t)b * N + n0 + n) * Y2C + ct * 32 + 2 * cp) = lo | (hi << 16);
    }
}

// ---------------- K5: out = W' @ [y1t; y2t] + bias
// LDS-staged MFMA GEMM (m97 structure): 128o x 128n tile, BK=32, 4 waves.
__global__ __launch_bounds__(256) void k_proj(const short* __restrict__ Wp,
                                              const short* __restrict__ y1t,
                                              const short* __restrict__ y2t,
                                              const float* __restrict__ bias,
                                              float* __restrict__ out) {
    __shared__ short Asl[128 * 32];
    __shared__ short Bsl[128 * 32];
    int b = blockIdx.x, ob = blockIdx.y, nb = blockIdx.z;
    int tid = threadIdx.x, w = tid >> 6, l = tid & 63;
    int col = l & 31, hi = l >> 5;
    int wr = w >> 1, wc = w & 1;
    int o0 = ob * 128, n0 = nb * 128;
    size_t bn = (size_t)b * N + n0;

    f32x16 acc[2][2];
    acc[0][0] = zero16(); acc[0][1] = zero16();
    acc[1][0] = zero16(); acc[1][1] = zero16();

    int srow = (l >> 2);        // 0..15 within a 16-row issue
    int sslotbase = (l & 3);    // 16B slot within 64B row

    for (int step = 0; step < 12; step++) {
        int k0 = step * 32;
        const short* ysrc;
        int ystride, kq;
        if (k0 < PD) { ysrc = y1t; ystride = PD;  kq = k0; }
        else         { ysrc = y2t; ystride = Y2C; kq = k0 - PD; }
        #pragma unroll
        for (int i = 0; i < 2; i++) {
            int row = w * 32 + i * 16 + srow;
            int sl = sslotbase ^ (row & 3);
            GLOAD16(Wp + (size_t)(o0 + row) * DIM + k0 + sl * 8,
                    &Asl[(w * 32 + i * 16) * 32]);
            GLOAD16(ysrc + (bn + row) * ystride + kq + sl * 8,
                    &Bsl[(w * 32 + i * 16) * 32]);
        }
        __syncthreads();
        #pragma unroll
        for (int kh = 0; kh < 2; kh++) {
            int bxor = ((kh << 5) + (hi << 4));
            int ra0 = wr * 64 + col,      ra1 = ra0 + 32;
            int rb0 = wc * 64 + col,      rb1 = rb0 + 32;
            bf16x8 a0 = *(const bf16x8*)&Asl[ra0 * 32 + ((bxor ^ ((ra0 & 3) << 4)) >> 1)];
            bf16x8 a1 = *(const bf16x8*)&Asl[ra1 * 32 + ((bxor ^ ((ra1 & 3) << 4)) >> 1)];
            bf16x8 b0 = *(const bf16x8*)&Bsl[rb0 * 32 + ((bxor ^ ((rb0 & 3) << 4)) >> 1)];
            bf16x8 b1 = *(const bf16x8*)&Bsl[rb1 * 32 + ((bxor ^ ((rb1 & 3) << 4)) >> 1)];
            acc[0][0] = MFMA(a0, b0, acc[0][0]);
            acc[0][1] = MFMA(a0, b1, acc[0][1]);
            acc[1][0] = MFMA(a1, b0, acc[1][0]);
            acc[1][1] = MFMA(a1, b1, acc[1][1]);
        }
        __syncthreads();
    }
    #pragma unroll
    for (int m = 0; m < 2; m++) {
        #pragma unroll
        for (int n = 0; n < 2; n++) {
            #pragma unroll
            for (int r = 0; r < 16; r++) {
                int o = o0 + wr * 64 + m * 32 + (r & 3) + 8 * (r >> 2) + 4 * hi;
                out[((size_t)b * DIM + o) * N + n0 + wc * 64 + n * 32 + col] =
                    acc[m][n][r] + bias[o];
            }
        }
    }
}

// -----------------------------------------------------------------------------
// ws layout (~50.7 MB): y2t (37.75 MB) aliases [Qt,Kt,Vw]+tail (dead after
// k_attn; k_trans runs after k_attn on the same stream; rewritten every call).
extern "C" void kernel_launch(void* const* d_in, const int* in_sizes, int n_in,
                              void* d_out, int out_size, void* d_ws, size_t ws_size,
                              hipStream_t stream) {
    const float* x    = (const float*)d_in[0];
    const float* gnw  = (const float*)d_in[1];
    const float* gnb  = (const float*)d_in[2];
    const float* qkvw = (const float*)d_in[3];
    const float* qbnw = (const float*)d_in[4];
    const float* qbnb = (const float*)d_in[5];
    const float* qbnm = (const float*)d_in[6];
    const float* qbnv = (const float*)d_in[7];
    const float* pw   = (const float*)d_in[8];
    const float* pbnw = (const float*)d_in[9];
    const float* pbnb = (const float*)d_in[10];
    const float* pbnm = (const float*)d_in[11];
    const float* pbnv = (const float*)d_in[12];
    float* out = (float*)d_out;

    char* p = (char*)d_ws;
    float* part  = (float*)p;  p += 4096;                      // 64*8*2 floats
    short* Wp    = (short*)p;  p += (size_t)DIM * DIM * 2;     // 288 KB
    float* bias  = (float*)p;  p += 1536;                      // DIM*4
    short* Wq    = (short*)p;  p += (size_t)OQ * PD * 2;       // 24 KB
    float* qbias = (float*)p;  p += 512;                       // OQ*4
    short* y1t   = (short*)p;  p += (size_t)B * N * PD * 2;    // 12.6 MB
    short* Qt    = (short*)p;                                  // 2 MB   (dead after attn)
    short* Kt    = Qt + (size_t)B * N * QKD;                   // 2 MB   (dead after attn)
    short* Vw    = Kt + (size_t)B * N * QKD;                   // 12.6 MB(dead after attn)
    short* y2t   = Qt;                                         // 37.75 MB alias

    k_pre<<<1136, 256, 0, stream>>>(x, part, pw, pbnw, pbnb, pbnm, pbnv, Wp, bias,
                                    qkvw, qbnw, qbnb, qbnm, qbnv, Wq, qbias);
    k_qkv<<<dim3(B, 8), 256, 0, stream>>>(x, part, gnw, gnb, Wq, qbias, Qt, Kt, Vw);
    k_attn<<<dim3(B, 8), 512, 0, stream>>>(Qt, Kt, Vw, y1t);
    k_trans<<<dim3(B, 9, 8), 256, 0, stream>>>(x, y2t);
    k_proj<<<dim3(B, 3, 8), 256, 0, stream>>>(Wp, y1t, y2t, bias, out);
}

// Round 18
// 105.405 us; speedup vs baseline: 1.3587x; 1.0276x over previous
//
#include <hip/hip_runtime.h>

#define EPS 1e-5f

constexpr int B   = 64;
constexpr int DIM = 384;
constexpr int PD  = 96;    // PDIM
constexpr int QKD = 16;    // QK
constexpr int N   = 1024;  // H*W
constexpr int OQ  = 128;   // 2*QK + PDIM
constexpr int Y2C = DIM - PD;  // 288
constexpr int VST = 72;    // V-tile LDS row stride (shorts); 144B = 16B-aligned rows
// 0.25 (softmax scale) * log2(e): folded into Q so QK^T lands in exp2-domain
#define QSCALE 0.3606737602222408f

typedef __attribute__((ext_vector_type(8))) short bf16x8;
typedef __attribute__((ext_vector_type(16))) float f32x16;

#define MFMA(a, b, c) __builtin_amdgcn_mfma_f32_32x32x16_bf16((a), (b), (c), 0, 0, 0)

// async global->LDS, 16B per lane; LDS dest is wave-uniform base + lane*16
#define GLOAD16(gsrc, ldst)                                                    \
    __builtin_amdgcn_global_load_lds(                                          \
        (const __attribute__((address_space(1))) void*)(gsrc),                 \
        (__attribute__((address_space(3))) void*)(ldst), 16, 0, 0)

__device__ __forceinline__ unsigned short f2bf(float f) {
    union { float f; unsigned u; } v; v.f = f;
    unsigned r = v.u + 0x7fffu + ((v.u >> 16) & 1u);
    return (unsigned short)(r >> 16);
}
__device__ __forceinline__ unsigned pack2(float a, float b) {
    return (unsigned)f2bf(a) | ((unsigned)f2bf(b) << 16);
}
// hardware packed f32->bf16 (RNE), 1 VALU op for 2 values
__device__ __forceinline__ unsigned cvtpk(float lo, float hi_) {
    unsigned r;
    asm("v_cvt_pk_bf16_f32 %0, %1, %2" : "=v"(r) : "v"(lo), "v"(hi_));
    return r;
}
__device__ __forceinline__ float max3f(float a, float b, float c) {
    return fmaxf(fmaxf(a, b), c);   // clang fuses to v_max3_f32
}
__device__ __forceinline__ f32x16 zero16() {
    f32x16 z;
#pragma unroll
    for (int i = 0; i < 16; i++) z[i] = 0.f;
    return z;
}

// ---------------- K1: fused pre-pass.
// blocks 0..511: GN partial sums, 8 blocks per batch (12 float4/thread,
//   fully unrolled, 4 accumulators -> loads pipelined, not serialized).
// blocks 512..1087: Wp conv.  blocks 1088..1135: Wq conv.
__global__ __launch_bounds__(256) void k_pre(const float* __restrict__ x,
                                             float* __restrict__ part,
                                             const float* __restrict__ pw,
                                             const float* __restrict__ pbnw,
                                             const float* __restrict__ pbnb,
                                             const float* __restrict__ pbnm,
                                             const float* __restrict__ pbnv,
                                             short* __restrict__ Wp,
                                             float* __restrict__ bias,
                                             const float* __restrict__ qw,
                                             const float* __restrict__ qbnw,
                                             const float* __restrict__ qbnb,
                                             const float* __restrict__ qbnm,
                                             const float* __restrict__ qbnv,
                                             short* __restrict__ Wq,
                                             float* __restrict__ qbias) {
    __shared__ float r1[4], r2[4];
    int gb = blockIdx.x;
    int tid = threadIdx.x;
    if (gb < 512) {                      // ---- GN partial sums: batch gb>>3, part gb&7
        int b = gb >> 3, p = gb & 7;
        const float4* xp = (const float4*)(x + (size_t)b * DIM * N) + p * 3072;
        float s1a = 0.f, s1b = 0.f, s1c = 0.f, s1d = 0.f;
        float s2a = 0.f, s2b = 0.f, s2c = 0.f, s2d = 0.f;
        #pragma unroll
        for (int i = 0; i < 12; i += 4) {
            float4 v0 = xp[tid + (i + 0) * 256];
            float4 v1 = xp[tid + (i + 1) * 256];
            float4 v2 = xp[tid + (i + 2) * 256];
            float4 v3 = xp[tid + (i + 3) * 256];
            s1a += v0.x + v0.y + v0.z + v0.w;
            s2a += v0.x * v0.x + v0.y * v0.y + v0.z * v0.z + v0.w * v0.w;
            s1b += v1.x + v1.y + v1.z + v1.w;
            s2b += v1.x * v1.x + v1.y * v1.y + v1.z * v1.z + v1.w * v1.w;
            s1c += v2.x + v2.y + v2.z + v2.w;
            s2c += v2.x * v2.x + v2.y * v2.y + v2.z * v2.z + v2.w * v2.w;
            s1d += v3.x + v3.y + v3.z + v3.w;
            s2d += v3.x * v3.x + v3.y * v3.y + v3.z * v3.z + v3.w * v3.w;
        }
        float s1 = (s1a + s1b) + (s1c + s1d);
        float s2 = (s2a + s2b) + (s2c + s2d);
        for (int o = 32; o > 0; o >>= 1) {
            s1 += __shfl_down(s1, o, 64);
            s2 += __shfl_down(s2, o, 64);
        }
        int wave = tid >> 6, lane = tid & 63;
        if (lane == 0) { r1[wave] = s1; r2[wave] = s2; }
        __syncthreads();
        if (tid == 0) {
            part[(b * 8 + p) * 2 + 0] = r1[0] + r1[1] + r1[2] + r1[3];
            part[(b * 8 + p) * 2 + 1] = r2[0] + r2[1] + r2[2] + r2[3];
        }
    } else if (gb < 512 + 576) {         // ---- Wp = bf16(proj_w * bn_inv)
        int idx = (gb - 512) * 256 + tid;
        int o = idx / DIM;
        float inv = pbnw[o] * rsqrtf(pbnv[o] + EPS);
        Wp[idx] = (short)f2bf(pw[idx] * inv);
        if (idx < DIM) bias[idx] = pbnb[idx] - pbnm[idx] * (pbnw[idx] * rsqrtf(pbnv[idx] + EPS));
    } else {                             // ---- Wq = bf16(qkv_w * bn_inv * qscale)
        int idx = (gb - 1088) * 256 + tid;
        int o = idx / PD;
        float inv = qbnw[o] * rsqrtf(qbnv[o] + EPS);
        float f = (o < QKD) ? QSCALE : 1.f;
        Wq[idx] = (short)f2bf(qw[idx] * inv * f);
        if (idx < OQ) {
            float invb = qbnw[idx] * rsqrtf(qbnv[idx] + EPS);
            float fb = (idx < QKD) ? QSCALE : 1.f;
            qbias[idx] = (qbnb[idx] - qbnm[idx] * invb) * fb;
        }
    }
}

// ---------------- K2: MFMA QKV GEMM with fused GN+transpose staging.
// [128 o] x [128 n], K=96 single-shot. mu/rsig reduced from the 16 partials
// at block start (LDS broadcast). B-operand built from x directly.
// V columns are stored PERMUTED within each 16-key group (quads 1<->2
// swapped: n' = (n&~12)|((n&4)<<1)|((n&8)>>1)) so that attn's PV MFMA can
// build its P B-fragments lane-locally with ZERO cross-lane shuffles.
__global__ __launch_bounds__(256) void k_qkv(const float* __restrict__ x,
                                             const float* __restrict__ part,
                                             const float* __restrict__ gnw,
                                             const float* __restrict__ gnb,
                                             const short* __restrict__ Wq,
                                             const float* __restrict__ qbias,
                                             short* __restrict__ Qt,
                                             short* __restrict__ Kt,
                                             short* __restrict__ Vw) {
    alignas(16) __shared__ short Wl[128 * 104];
    alignas(16) __shared__ short Xl[128 * 104];
    __shared__ short t[32][132];
    __shared__ float qbl[OQ];
    __shared__ float pr[16];
    int b = blockIdx.x, nb = blockIdx.y;
    int tid = threadIdx.x, w = tid >> 6, l = tid & 63;
    int col = l & 31, hi = l >> 5;
    int wr = w >> 1, wc = w & 1;
    int n0 = nb * 128;

    if (tid < 16) pr[tid] = part[b * 16 + tid];
    if (tid >= 64 && tid < 64 + OQ) qbl[tid - 64] = qbias[tid - 64];
    #pragma unroll
    for (int it = 0; it < 6; it++) {
        int e = tid + 256 * it;          // 0..1535
        int row = e / 12, slot = e % 12;
        *(uint4*)&Wl[row * 104 + slot * 8] = *(const uint4*)(Wq + row * PD + slot * 8);
    }
    __syncthreads();
    float s1 = (pr[0] + pr[2]) + (pr[4] + pr[6]) + (pr[8] + pr[10]) + (pr[12] + pr[14]);
    float s2 = (pr[1] + pr[3]) + (pr[5] + pr[7]) + (pr[9] + pr[11]) + (pr[13] + pr[15]);
    float mu = s1 / (PD * N);
    float var = s2 / (PD * N) - mu * mu;
    float rsig = rsqrtf(var + EPS);

    const float* xb = x + (size_t)b * DIM * N + n0;
    for (int ct = 0; ct < 3; ct++) {
        int c0 = ct * 32;
        if (ct) __syncthreads();         // protect t reuse across chunks
        #pragma unroll
        for (int i = 0; i < 4; i++) {
            int e = tid + 256 * i;
            int c = e >> 5, q4 = e & 31;
            float4 v = *(const float4*)(xb + (size_t)(c0 + c) * N + q4 * 4);
            float s = rsig * gnw[c0 + c];
            float tt = gnb[c0 + c] - mu * s;
            uint2 d;
            d.x = pack2(s * v.x + tt, s * v.y + tt);
            d.y = pack2(s * v.z + tt, s * v.w + tt);
            *(uint2*)&t[c][q4 * 4] = d;
        }
        __syncthreads();
        #pragma unroll
        for (int i = 0; i < 8; i++) {
            int e = tid + 256 * i;
            int n = e >> 4, cp = e & 15;
            unsigned lo = (unsigned short)t[2 * cp][n];
            unsigned hi2 = (unsigned short)t[2 * cp + 1][n];
            *(unsigned*)&Xl[n * 104 + c0 + 2 * cp] = lo | (hi2 << 16);
        }
    }
    __syncthreads();

    f32x16 acc[2][2];
    acc[0][0] = zero16(); acc[0][1] = zero16();
    acc[1][0] = zero16(); acc[1][1] = zero16();
    #pragma unroll
    for (int ks = 0; ks < 6; ks++) {
        int ko = ks * 16 + hi * 8;
        int ra0 = wr * 64 + col, ra1 = ra0 + 32;
        int rb0 = wc * 64 + col, rb1 = rb0 + 32;
        bf16x8 a0 = *(const bf16x8*)&Wl[ra0 * 104 + ko];
        bf16x8 a1 = *(const bf16x8*)&Wl[ra1 * 104 + ko];
        bf16x8 b0 = *(const bf16x8*)&Xl[rb0 * 104 + ko];
        bf16x8 b1 = *(const bf16x8*)&Xl[rb1 * 104 + ko];
        acc[0][0] = MFMA(a0, b0, acc[0][0]);
        acc[0][1] = MFMA(a0, b1, acc[0][1]);
        acc[1][0] = MFMA(a1, b0, acc[1][0]);
        acc[1][1] = MFMA(a1, b1, acc[1][1]);
    }

    #pragma unroll
    for (int m = 0; m < 2; m++) {
        int o_base = wr * 64 + m * 32;
        #pragma unroll
        for (int nn = 0; nn < 2; nn++) {
            int n = n0 + wc * 64 + nn * 32 + col;
            f32x16 a = acc[m][nn];
            if (o_base == 0) {
                // o 0..15 -> Q, 16..31 -> K
                #pragma unroll
                for (int g = 0; g < 4; g++) {
                    int ofr = 8 * g + 4 * hi;   // frag-o base: 0,8,16,24 (+4hi)
                    float v0 = a[4 * g + 0] + qbl[ofr + 0];
                    float v1 = a[4 * g + 1] + qbl[ofr + 1];
                    float v2 = a[4 * g + 2] + qbl[ofr + 2];
                    float v3 = a[4 * g + 3] + qbl[ofr + 3];
                    uint2 d; d.x = pack2(v0, v1); d.y = pack2(v2, v3);
                    short* dst = (g < 2)
                        ? (Qt + ((size_t)b * N + n) * QKD + (ofr & 15))
                        : (Kt + ((size_t)b * N + n) * QKD + (ofr & 15));
                    *(uint2*)dst = d;
                }
            } else {
                int c0 = o_base - 32;          // 0, 32, 64
                // permuted V column: swap key-quads 1<->2 within each 16-group
                int np = (n & ~12) | ((n & 4) << 1) | ((n & 8) >> 1);
                short* vb = Vw + ((size_t)b * PD + c0) * N + np;
                #pragma unroll
                for (int r = 0; r < 16; r++) {
                    int cf = (r & 3) + 8 * (r >> 2) + 4 * hi;
                    vb[(size_t)cf * N] = (short)f2bf(a[r] + qbl[32 + c0 + cf]);
                }
            }
        }
    }
}

// ---------------------------------------- K3: MFMA flash attention, LDS-staged V
// grid (B, 8), 512 threads = 8 waves = 4 q-tiles x 2 key-splits (512 keys each).
// One softmax update per 64 keys. V staged via LDS double-buffer, T14
// issue-early/write-late. V columns pre-permuted (k_qkv) so P B-fragments are
// built LANE-LOCALLY: pb0 = pw[0..3], pb1 = pw[4..7] -- no cross-lane shuffles.
__global__ __launch_bounds__(512, 2) void k_attn(const short* __restrict__ Qt,
                                                 const short* __restrict__ Kt,
                                                 const short* __restrict__ Vb,
                                                 short* __restrict__ y1t) {
    alignas(16) __shared__ char lds_raw[4 * 96 * VST * 2];  // 55296 B
    short* Vs = (short*)lds_raw;   // [split][buf][96*VST]
    float* combA_ = (float*)lds_raw;               // [4][64][49] = 50176 B
    float* combM_ = (float*)(lds_raw + 50176);     // [4][64]
    float* combL_ = (float*)(lds_raw + 51200);     // [4][64]

    int b = blockIdx.x;
    int tid = threadIdx.x;
    int split = tid >> 8;
    int s_tid = tid & 255;
    int w = tid >> 6, lane = tid & 63;
    int qgrp = w & 3;
    int col = lane & 31, hi = lane >> 5;
    int q0 = blockIdx.y * 128 + qgrp * 32;
    int kbeg = split * 512;

    const short* kbase = Kt + (size_t)b * N * QKD;
    const short* vbase = Vb + (size_t)b * PD * N;
    const bf16x8 qf = *(const bf16x8*)(Qt + ((size_t)b * N + q0 + col) * QKD + hi * 8);

    short* vs0 = Vs + (split * 2 + 0) * (96 * VST);
    short* vs1 = Vs + (split * 2 + 1) * (96 * VST);

    bf16x8 kf0 = *(const bf16x8*)(kbase + (size_t)(kbeg + col) * QKD + hi * 8);
    bf16x8 kf1 = *(const bf16x8*)(kbase + (size_t)(kbeg + 32 + col) * QKD + hi * 8);
    {
        int t0 = s_tid, t1 = s_tid + 256, t2i = s_tid + 512;
        uint4 g0 = *(const uint4*)(vbase + (size_t)(t0 >> 3) * N + kbeg + (t0 & 7) * 8);
        uint4 g1 = *(const uint4*)(vbase + (size_t)(t1 >> 3) * N + kbeg + (t1 & 7) * 8);
        uint4 g2 = *(const uint4*)(vbase + (size_t)(t2i >> 3) * N + kbeg + (t2i & 7) * 8);
        *(uint4*)(vs0 + (t0 >> 3) * VST + (t0 & 7) * 8) = g0;
        *(uint4*)(vs0 + (t1 >> 3) * VST + (t1 & 7) * 8) = g1;
        *(uint4*)(vs0 + (t2i >> 3) * VST + (t2i & 7) * 8) = g2;
    }
    __syncthreads();

    f32x16 acc0 = zero16(), acc1 = zero16(), acc2 = zero16();
    float m = -1e30f, lsum = 0.f;

    for (int it = 0; it < 8; it++) {
        int m0 = kbeg + it * 64;
        short* cur = (it & 1) ? vs1 : vs0;
        short* nxt = (it & 1) ? vs0 : vs1;
        bool more = (it < 7);
        int m0n = more ? m0 + 64 : m0;
        bf16x8 kf0n = *(const bf16x8*)(kbase + (size_t)(m0n + col) * QKD + hi * 8);
        bf16x8 kf1n = *(const bf16x8*)(kbase + (size_t)(m0n + 32 + col) * QKD + hi * 8);
        uint4 g0, g1, g2;
        if (more) {
            int t0 = s_tid, t1 = s_tid + 256, t2i = s_tid + 512;
            g0 = *(const uint4*)(vbase + (size_t)(t0 >> 3) * N + m0n + (t0 & 7) * 8);
            g1 = *(const uint4*)(vbase + (size_t)(t1 >> 3) * N + m0n + (t1 & 7) * 8);
            g2 = *(const uint4*)(vbase + (size_t)(t2i >> 3) * N + m0n + (t2i & 7) * 8);
        }

        f32x16 s0 = MFMA(kf0, qf, zero16());
        f32x16 s1 = MFMA(kf1, qf, zero16());
        float a0 = max3f(s0[0], s0[1], s0[2]),  a1 = max3f(s0[3], s0[4], s0[5]);
        float a2 = max3f(s0[6], s0[7], s0[8]),  a3 = max3f(s0[9], s0[10], s0[11]);
        float a4 = max3f(s0[12], s0[13], s0[14]);
        float cm0 = fmaxf(max3f(a0, a1, a2), max3f(a3, a4, s0[15]));
        float b0_ = max3f(s1[0], s1[1], s1[2]),  b1_ = max3f(s1[3], s1[4], s1[5]);
        float b2_ = max3f(s1[6], s1[7], s1[8]),  b3_ = max3f(s1[9], s1[10], s1[11]);
        float b4_ = max3f(s1[12], s1[13], s1[14]);
        float cm1 = fmaxf(max3f(b0_, b1_, b2_), max3f(b3_, b4_, s1[15]));
        float cm = fmaxf(cm0, cm1);
        cm = fmaxf(cm, __shfl_xor(cm, 32, 64));
        if (!__all(cm <= m + 8.f)) {       // defer-max (T13), once per 64 keys
            float mnew = fmaxf(m, cm);
            float corr = __builtin_amdgcn_exp2f(m - mnew);
            m = mnew;
            lsum *= corr;
            #pragma unroll
            for (int r = 0; r < 16; r++) { acc0[r] *= corr; acc1[r] *= corr; acc2[r] *= corr; }
        }
        // exponentiate; fragments are lane-local thanks to the V permutation
        float ps = 0.f;
        bf16x8 pbv[2][2];
        #pragma unroll
        for (int s32 = 0; s32 < 2; s32++) {
            const f32x16& s = s32 ? s1 : s0;
            unsigned pw[8];
            #pragma unroll
            for (int j = 0; j < 8; j++) {
                float p0 = __builtin_amdgcn_exp2f(s[2 * j] - m);
                float p1 = __builtin_amdgcn_exp2f(s[2 * j + 1] - m);
                ps += p0 + p1;
                pw[j] = cvtpk(p0, p1);
            }
            union { unsigned u[4]; bf16x8 v; } pb0, pb1;
            pb0.u[0] = pw[0]; pb0.u[1] = pw[1]; pb0.u[2] = pw[2]; pb0.u[3] = pw[3];
            pb1.u[0] = pw[4]; pb1.u[1] = pw[5]; pb1.u[2] = pw[6]; pb1.u[3] = pw[7];
            pbv[s32][0] = pb0.v;
            pbv[s32][1] = pb1.v;
        }
        ps += __shfl_xor(ps, 32, 64);
        lsum += ps;
        __builtin_amdgcn_s_setprio(1);
        #pragma unroll
        for (int s32 = 0; s32 < 2; s32++) {
            const short* vt32 = cur + s32 * 32 + hi * 8;
            bf16x8 pa = pbv[s32][0], pq = pbv[s32][1];
            bf16x8 va0 = *(const bf16x8*)(vt32 + col * VST);
            bf16x8 va1 = *(const bf16x8*)(vt32 + col * VST + 16);
            acc0 = MFMA(va0, pa, acc0);
            acc0 = MFMA(va1, pq, acc0);
            bf16x8 vb0 = *(const bf16x8*)(vt32 + (32 + col) * VST);
            bf16x8 vb1 = *(const bf16x8*)(vt32 + (32 + col) * VST + 16);
            acc1 = MFMA(vb0, pa, acc1);
            acc1 = MFMA(vb1, pq, acc1);
            bf16x8 vc0 = *(const bf16x8*)(vt32 + (64 + col) * VST);
            bf16x8 vc1 = *(const bf16x8*)(vt32 + (64 + col) * VST + 16);
            acc2 = MFMA(vc0, pa, acc2);
            acc2 = MFMA(vc1, pq, acc2);
        }
        __builtin_amdgcn_s_setprio(0);
        kf0 = kf0n; kf1 = kf1n;
        if (more) {
            int t0 = s_tid, t1 = s_tid + 256, t2i = s_tid + 512;
            *(uint4*)(nxt + (t0 >> 3) * VST + (t0 & 7) * 8) = g0;
            *(uint4*)(nxt + (t1 >> 3) * VST + (t1 & 7) * 8) = g1;
            *(uint4*)(nxt + (t2i >> 3) * VST + (t2i & 7) * 8) = g2;
            __syncthreads();
        }
    }

    __syncthreads();
    if (split == 1) {
        float* dst = combA_ + (qgrp * 64 + lane) * 49;
        #pragma unroll
        for (int r = 0; r < 16; r++) {
            dst[r] = acc0[r]; dst[16 + r] = acc1[r]; dst[32 + r] = acc2[r];
        }
        combM_[qgrp * 64 + lane] = m;
        combL_[qgrp * 64 + lane] = lsum;
    }
    __syncthreads();
    if (split == 0) {
        float m2 = combM_[qgrp * 64 + lane], l2 = combL_[qgrp * 64 + lane];
        float M  = fmaxf(m, m2);
        float c1 = __builtin_amdgcn_exp2f(m - M);
        float c2 = __builtin_amdgcn_exp2f(m2 - M);
        float inv = 1.f / (lsum * c1 + l2 * c2);
        const float* src = combA_ + (qgrp * 64 + lane) * 49;
        float f1 = c1 * inv, f2 = c2 * inv;
        short* yrow = y1t + ((size_t)b * N + q0 + col) * PD;
        #pragma unroll
        for (int cg = 0; cg < 3; cg++) {
            f32x16 a = (cg == 0) ? acc0 : ((cg == 1) ? acc1 : acc2);
            const float* sr = src + cg * 16;
            #pragma unroll
            for (int j = 0; j < 8; j++) {
                float v0 = a[2 * j] * f1 + sr[2 * j] * f2;
                float v1 = a[2 * j + 1] * f1 + sr[2 * j + 1] * f2;
                v0 = v0 / (1.f + __expf(-v0));   // silu
                v1 = v1 / (1.f + __expf(-v1));
                int c = cg * 32 + ((2 * j) & 3) + 8 * (j >> 1) + 4 * hi;
                *(unsigned*)(yrow + c) = pack2(v0, v1);
            }
        }
    }
}

// ---------------- K4: y2t[b][n][c-96] = bf16(silu(x[b][c][n])) (float4 reads)
__global__ __launch_bounds__(256) void k_trans(const float* __restrict__ x,
                                               short* __restrict__ y2t) {
    int b = blockIdx.x, ct = blockIdx.y, nt = blockIdx.z;
    int tid = threadIdx.x;
    __shared__ short t[32][132];
    int c0 = PD + ct * 32, n0 = nt * 128;
    const float* xb = x + ((size_t)b * DIM + c0) * N + n0;
    #pragma unroll
    for (int i = 0; i < 4; i++) {
        int e = tid + 256 * i;
        int c = e >> 5, q4 = e & 31;
        float4 v = *(const float4*)(xb + (size_t)c * N + q4 * 4);
        float s0 = v.x / (1.f + __expf(-v.x));
        float s1 = v.y / (1.f + __expf(-v.y));
        float s2 = v.z / (1.f + __expf(-v.z));
        float s3 = v.w / (1.f + __expf(-v.w));
        uint2 d;
        d.x = pack2(s0, s1);
        d.y = pack2(s2, s3);
        *(uint2*)&t[c][q4 * 4] = d;
    }
    __syncthreads();
    #pragma unroll
    for (int i = 0; i < 8; i++) {
        int e = tid + 256 * i;
        int n = e >> 4, cp = e & 15;
        unsigned lo = (unsigned short)t[2 * cp][n];
        unsigned hi = (unsigned short)t[2 * cp + 1][n];
        *(unsigned*)(y2t + ((size_t)b * N + n0 + n) * Y2C + ct * 32 + 2 * cp) = lo | (hi << 16);
    }
}

// ---------------- K5: out = W' @ [y1t; y2t] + bias
// LDS-staged MFMA GEMM (m97 structure): 128o x 128n tile, BK=32, 4 waves.
__global__ __launch_bounds__(256) void k_proj(const short* __restrict__ Wp,
                                              const short* __restrict__ y1t,
                                              const short* __restrict__ y2t,
                                              const float* __restrict__ bias,
                                              float* __restrict__ out) {
    __shared__ short Asl[128 * 32];
    __shared__ short Bsl[128 * 32];
    int b = blockIdx.x, ob = blockIdx.y, nb = blockIdx.z;
    int tid = threadIdx.x, w = tid >> 6, l = tid & 63;
    int col = l & 31, hi = l >> 5;
    int wr = w >> 1, wc = w & 1;
    int o0 = ob * 128, n0 = nb * 128;
    size_t bn = (size_t)b * N + n0;

    f32x16 acc[2][2];
    acc[0][0] = zero16(); acc[0][1] = zero16();
    acc[1][0] = zero16(); acc[1][1] = zero16();

    int srow = (l >> 2);        // 0..15 within a 16-row issue
    int sslotbase = (l & 3);    // 16B slot within 64B row

    for (int step = 0; step < 12; step++) {
        int k0 = step * 32;
        const short* ysrc;
        int ystride, kq;
        if (k0 < PD) { ysrc = y1t; ystride = PD;  kq = k0; }
        else         { ysrc = y2t; ystride = Y2C; kq = k0 - PD; }
        #pragma unroll
        for (int i = 0; i < 2; i++) {
            int row = w * 32 + i * 16 + srow;
            int sl = sslotbase ^ (row & 3);
            GLOAD16(Wp + (size_t)(o0 + row) * DIM + k0 + sl * 8,
                    &Asl[(w * 32 + i * 16) * 32]);
            GLOAD16(ysrc + (bn + row) * ystride + kq + sl * 8,
                    &Bsl[(w * 32 + i * 16) * 32]);
        }
        __syncthreads();
        #pragma unroll
        for (int kh = 0; kh < 2; kh++) {
            int bxor = ((kh << 5) + (hi << 4));
            int ra0 = wr * 64 + col,      ra1 = ra0 + 32;
            int rb0 = wc * 64 + col,      rb1 = rb0 + 32;
            bf16x8 a0 = *(const bf16x8*)&Asl[ra0 * 32 + ((bxor ^ ((ra0 & 3) << 4)) >> 1)];
            bf16x8 a1 = *(const bf16x8*)&Asl[ra1 * 32 + ((bxor ^ ((ra1 & 3) << 4)) >> 1)];
            bf16x8 b0 = *(const bf16x8*)&Bsl[rb0 * 32 + ((bxor ^ ((rb0 & 3) << 4)) >> 1)];
            bf16x8 b1 = *(const bf16x8*)&Bsl[rb1 * 32 + ((bxor ^ ((rb1 & 3) << 4)) >> 1)];
            acc[0][0] = MFMA(a0, b0, acc[0][0]);
            acc[0][1] = MFMA(a0, b1, acc[0][1]);
            acc[1][0] = MFMA(a1, b0, acc[1][0]);
            acc[1][1] = MFMA(a1, b1, acc[1][1]);
        }
        __syncthreads();
    }
    #pragma unroll
    for (int m = 0; m < 2; m++) {
        #pragma unroll
        for (int n = 0; n < 2; n++) {
            #pragma unroll
            for (int r = 0; r < 16; r++) {
                int o = o0 + wr * 64 + m * 32 + (r & 3) + 8 * (r >> 2) + 4 * hi;
                out[((size_t)b * DIM + o) * N + n0 + wc * 64 + n * 32 + col] =
                    acc[m][n][r] + bias[o];
            }
        }
    }
}

// -----------------------------------------------------------------------------
// ws layout (~50.7 MB): y2t (37.75 MB) aliases [Qt,Kt,Vw]+tail (dead after
// k_attn; k_trans runs after k_attn on the same stream; rewritten every call).
extern "C" void kernel_launch(void* const* d_in, const int* in_sizes, int n_in,
                              void* d_out, int out_size, void* d_ws, size_t ws_size,
                              hipStream_t stream) {
    const float* x    = (const float*)d_in[0];
    const float* gnw  = (const float*)d_in[1];
    const float* gnb  = (const float*)d_in[2];
    const float* qkvw = (const float*)d_in[3];
    const float* qbnw = (const float*)d_in[4];
    const float* qbnb = (const float*)d_in[5];
    const float* qbnm = (const float*)d_in[6];
    const float* qbnv = (const float*)d_in[7];
    const float* pw   = (const float*)d_in[8];
    const float* pbnw = (const float*)d_in[9];
    const float* pbnb = (const float*)d_in[10];
    const float* pbnm = (const float*)d_in[11];
    const float* pbnv = (const float*)d_in[12];
    float* out = (float*)d_out;

    char* p = (char*)d_ws;
    float* part  = (float*)p;  p += 4096;                      // 64*8*2 floats
    short* Wp    = (short*)p;  p += (size_t)DIM * DIM * 2;     // 288 KB
    float* bias  = (float*)p;  p += 1536;                      // DIM*4
    short* Wq    = (short*)p;  p += (size_t)OQ * PD * 2;       // 24 KB
    float* qbias = (float*)p;  p += 512;                       // OQ*4
    short* y1t   = (short*)p;  p += (size_t)B * N * PD * 2;    // 12.6 MB
    short* Qt    = (short*)p;                                  // 2 MB   (dead after attn)
    short* Kt    = Qt + (size_t)B * N * QKD;                   // 2 MB   (dead after attn)
    short* Vw    = Kt + (size_t)B * N * QKD;                   // 12.6 MB(dead after attn)
    short* y2t   = Qt;                                         // 37.75 MB alias

    k_pre<<<1136, 256, 0, stream>>>(x, part, pw, pbnw, pbnb, pbnm, pbnv, Wp, bias,
                                    qkvw, qbnw, qbnb, qbnm, qbnv, Wq, qbias);
    k_qkv<<<dim3(B, 8), 256, 0, stream>>>(x, part, gnw, gnb, Wq, qbias, Qt, Kt, Vw);
    k_attn<<<dim3(B, 8), 512, 0, stream>>>(Qt, Kt, Vw, y1t);
    k_trans<<<dim3(B, 9, 8), 256, 0, stream>>>(x, y2t);
    k_proj<<<dim3(B, 3, 8), 256, 0, stream>>>(Wp, y1t, y2t, bias, out);
}

// Round 19
// 103.326 us; speedup vs baseline: 1.3861x; 1.0201x over previous
//
#include <hip/hip_runtime.h>

#define EPS 1e-5f

constexpr int B   = 64;
constexpr int DIM = 384;
constexpr int PD  = 96;    // PDIM
constexpr int QKD = 16;    // QK
constexpr int N   = 1024;  // H*W
constexpr int OQ  = 128;   // 2*QK + PDIM
constexpr int Y2C = DIM - PD;  // 288
constexpr int VST = 72;    // V-tile LDS row stride (shorts); 144B = 16B-aligned rows
// 0.25 (softmax scale) * log2(e): folded into Q so QK^T lands in exp2-domain
#define QSCALE 0.3606737602222408f

typedef __attribute__((ext_vector_type(8))) short bf16x8;
typedef __attribute__((ext_vector_type(16))) float f32x16;

#define MFMA(a, b, c) __builtin_amdgcn_mfma_f32_32x32x16_bf16((a), (b), (c), 0, 0, 0)

// async global->LDS, 16B per lane; LDS dest is wave-uniform base + lane*16
#define GLOAD16(gsrc, ldst)                                                    \
    __builtin_amdgcn_global_load_lds(                                          \
        (const __attribute__((address_space(1))) void*)(gsrc),                 \
        (__attribute__((address_space(3))) void*)(ldst), 16, 0, 0)

__device__ __forceinline__ unsigned short f2bf(float f) {
    union { float f; unsigned u; } v; v.f = f;
    unsigned r = v.u + 0x7fffu + ((v.u >> 16) & 1u);
    return (unsigned short)(r >> 16);
}
__device__ __forceinline__ unsigned pack2(float a, float b) {
    return (unsigned)f2bf(a) | ((unsigned)f2bf(b) << 16);
}
// hardware packed f32->bf16 (RNE), 1 VALU op for 2 values
__device__ __forceinline__ unsigned cvtpk(float lo, float hi_) {
    unsigned r;
    asm("v_cvt_pk_bf16_f32 %0, %1, %2" : "=v"(r) : "v"(lo), "v"(hi_));
    return r;
}
__device__ __forceinline__ float max3f(float a, float b, float c) {
    return fmaxf(fmaxf(a, b), c);   // clang fuses to v_max3_f32
}
__device__ __forceinline__ f32x16 zero16() {
    f32x16 z;
#pragma unroll
    for (int i = 0; i < 16; i++) z[i] = 0.f;
    return z;
}

// ---------------- K1: fused pre-pass.
// blocks 0..511: GN partial sums, 8 blocks per batch (12 float4/thread,
//   fully unrolled, 4 accumulators -> loads pipelined, not serialized).
// blocks 512..1087: Wp conv.  blocks 1088..1135: Wq conv.
__global__ __launch_bounds__(256) void k_pre(const float* __restrict__ x,
                                             float* __restrict__ part,
                                             const float* __restrict__ pw,
                                             const float* __restrict__ pbnw,
                                             const float* __restrict__ pbnb,
                                             const float* __restrict__ pbnm,
                                             const float* __restrict__ pbnv,
                                             short* __restrict__ Wp,
                                             float* __restrict__ bias,
                                             const float* __restrict__ qw,
                                             const float* __restrict__ qbnw,
                                             const float* __restrict__ qbnb,
                                             const float* __restrict__ qbnm,
                                             const float* __restrict__ qbnv,
                                             short* __restrict__ Wq,
                                             float* __restrict__ qbias) {
    __shared__ float r1[4], r2[4];
    int gb = blockIdx.x;
    int tid = threadIdx.x;
    if (gb < 512) {                      // ---- GN partial sums: batch gb>>3, part gb&7
        int b = gb >> 3, p = gb & 7;
        const float4* xp = (const float4*)(x + (size_t)b * DIM * N) + p * 3072;
        float s1a = 0.f, s1b = 0.f, s1c = 0.f, s1d = 0.f;
        float s2a = 0.f, s2b = 0.f, s2c = 0.f, s2d = 0.f;
        #pragma unroll
        for (int i = 0; i < 12; i += 4) {
            float4 v0 = xp[tid + (i + 0) * 256];
            float4 v1 = xp[tid + (i + 1) * 256];
            float4 v2 = xp[tid + (i + 2) * 256];
            float4 v3 = xp[tid + (i + 3) * 256];
            s1a += v0.x + v0.y + v0.z + v0.w;
            s2a += v0.x * v0.x + v0.y * v0.y + v0.z * v0.z + v0.w * v0.w;
            s1b += v1.x + v1.y + v1.z + v1.w;
            s2b += v1.x * v1.x + v1.y * v1.y + v1.z * v1.z + v1.w * v1.w;
            s1c += v2.x + v2.y + v2.z + v2.w;
            s2c += v2.x * v2.x + v2.y * v2.y + v2.z * v2.z + v2.w * v2.w;
            s1d += v3.x + v3.y + v3.z + v3.w;
            s2d += v3.x * v3.x + v3.y * v3.y + v3.z * v3.z + v3.w * v3.w;
        }
        float s1 = (s1a + s1b) + (s1c + s1d);
        float s2 = (s2a + s2b) + (s2c + s2d);
        for (int o = 32; o > 0; o >>= 1) {
            s1 += __shfl_down(s1, o, 64);
            s2 += __shfl_down(s2, o, 64);
        }
        int wave = tid >> 6, lane = tid & 63;
        if (lane == 0) { r1[wave] = s1; r2[wave] = s2; }
        __syncthreads();
        if (tid == 0) {
            part[(b * 8 + p) * 2 + 0] = r1[0] + r1[1] + r1[2] + r1[3];
            part[(b * 8 + p) * 2 + 1] = r2[0] + r2[1] + r2[2] + r2[3];
        }
    } else if (gb < 512 + 576) {         // ---- Wp = bf16(proj_w * bn_inv)
        int idx = (gb - 512) * 256 + tid;
        int o = idx / DIM;
        float inv = pbnw[o] * rsqrtf(pbnv[o] + EPS);
        Wp[idx] = (short)f2bf(pw[idx] * inv);
        if (idx < DIM) bias[idx] = pbnb[idx] - pbnm[idx] * (pbnw[idx] * rsqrtf(pbnv[idx] + EPS));
    } else {                             // ---- Wq = bf16(qkv_w * bn_inv * qscale)
        int idx = (gb - 1088) * 256 + tid;
        int o = idx / PD;
        float inv = qbnw[o] * rsqrtf(qbnv[o] + EPS);
        float f = (o < QKD) ? QSCALE : 1.f;
        Wq[idx] = (short)f2bf(qw[idx] * inv * f);
        if (idx < OQ) {
            float invb = qbnw[idx] * rsqrtf(qbnv[idx] + EPS);
            float fb = (idx < QKD) ? QSCALE : 1.f;
            qbias[idx] = (qbnb[idx] - qbnm[idx] * invb) * fb;
        }
    }
}

// ---------------- K2: MFMA QKV GEMM with fused GN+transpose staging.
// [128 o] x [128 n], K=96 single-shot. mu/rsig reduced from the 16 partials
// at block start (LDS broadcast). B-operand built from x directly.
// V columns are stored PERMUTED within each 16-key group (quads 1<->2
// swapped: n' = (n&~12)|((n&4)<<1)|((n&8)>>1)) so that attn's PV MFMA can
// build its P B-fragments lane-locally with ZERO cross-lane shuffles.
__global__ __launch_bounds__(256) void k_qkv(const float* __restrict__ x,
                                             const float* __restrict__ part,
                                             const float* __restrict__ gnw,
                                             const float* __restrict__ gnb,
                                             const short* __restrict__ Wq,
                                             const float* __restrict__ qbias,
                                             short* __restrict__ Qt,
                                             short* __restrict__ Kt,
                                             short* __restrict__ Vw) {
    alignas(16) __shared__ short Wl[128 * 104];
    alignas(16) __shared__ short Xl[128 * 104];
    __shared__ short t[32][132];
    __shared__ float qbl[OQ];
    __shared__ float pr[16];
    int b = blockIdx.x, nb = blockIdx.y;
    int tid = threadIdx.x, w = tid >> 6, l = tid & 63;
    int col = l & 31, hi = l >> 5;
    int wr = w >> 1, wc = w & 1;
    int n0 = nb * 128;

    if (tid < 16) pr[tid] = part[b * 16 + tid];
    if (tid >= 64 && tid < 64 + OQ) qbl[tid - 64] = qbias[tid - 64];
    #pragma unroll
    for (int it = 0; it < 6; it++) {
        int e = tid + 256 * it;          // 0..1535
        int row = e / 12, slot = e % 12;
        *(uint4*)&Wl[row * 104 + slot * 8] = *(const uint4*)(Wq + row * PD + slot * 8);
    }
    __syncthreads();
    float s1 = (pr[0] + pr[2]) + (pr[4] + pr[6]) + (pr[8] + pr[10]) + (pr[12] + pr[14]);
    float s2 = (pr[1] + pr[3]) + (pr[5] + pr[7]) + (pr[9] + pr[11]) + (pr[13] + pr[15]);
    float mu = s1 / (PD * N);
    float var = s2 / (PD * N) - mu * mu;
    float rsig = rsqrtf(var + EPS);

    const float* xb = x + (size_t)b * DIM * N + n0;
    for (int ct = 0; ct < 3; ct++) {
        int c0 = ct * 32;
        if (ct) __syncthreads();         // protect t reuse across chunks
        #pragma unroll
        for (int i = 0; i < 4; i++) {
            int e = tid + 256 * i;
            int c = e >> 5, q4 = e & 31;
            float4 v = *(const float4*)(xb + (size_t)(c0 + c) * N + q4 * 4);
            float s = rsig * gnw[c0 + c];
            float tt = gnb[c0 + c] - mu * s;
            uint2 d;
            d.x = pack2(s * v.x + tt, s * v.y + tt);
            d.y = pack2(s * v.z + tt, s * v.w + tt);
            *(uint2*)&t[c][q4 * 4] = d;
        }
        __syncthreads();
        #pragma unroll
        for (int i = 0; i < 8; i++) {
            int e = tid + 256 * i;
            int n = e >> 4, cp = e & 15;
            unsigned lo = (unsigned short)t[2 * cp][n];
            unsigned hi2 = (unsigned short)t[2 * cp + 1][n];
            *(unsigned*)&Xl[n * 104 + c0 + 2 * cp] = lo | (hi2 << 16);
        }
    }
    __syncthreads();

    f32x16 acc[2][2];
    acc[0][0] = zero16(); acc[0][1] = zero16();
    acc[1][0] = zero16(); acc[1][1] = zero16();
    #pragma unroll
    for (int ks = 0; ks < 6; ks++) {
        int ko = ks * 16 + hi * 8;
        int ra0 = wr * 64 + col, ra1 = ra0 + 32;
        int rb0 = wc * 64 + col, rb1 = rb0 + 32;
        bf16x8 a0 = *(const bf16x8*)&Wl[ra0 * 104 + ko];
        bf16x8 a1 = *(const bf16x8*)&Wl[ra1 * 104 + ko];
        bf16x8 b0 = *(const bf16x8*)&Xl[rb0 * 104 + ko];
        bf16x8 b1 = *(const bf16x8*)&Xl[rb1 * 104 + ko];
        acc[0][0] = MFMA(a0, b0, acc[0][0]);
        acc[0][1] = MFMA(a0, b1, acc[0][1]);
        acc[1][0] = MFMA(a1, b0, acc[1][0]);
        acc[1][1] = MFMA(a1, b1, acc[1][1]);
    }

    #pragma unroll
    for (int m = 0; m < 2; m++) {
        int o_base = wr * 64 + m * 32;
        #pragma unroll
        for (int nn = 0; nn < 2; nn++) {
            int n = n0 + wc * 64 + nn * 32 + col;
            f32x16 a = acc[m][nn];
            if (o_base == 0) {
                // o 0..15 -> Q, 16..31 -> K
                #pragma unroll
                for (int g = 0; g < 4; g++) {
                    int ofr = 8 * g + 4 * hi;   // frag-o base: 0,8,16,24 (+4hi)
                    float v0 = a[4 * g + 0] + qbl[ofr + 0];
                    float v1 = a[4 * g + 1] + qbl[ofr + 1];
                    float v2 = a[4 * g + 2] + qbl[ofr + 2];
                    float v3 = a[4 * g + 3] + qbl[ofr + 3];
                    uint2 d; d.x = pack2(v0, v1); d.y = pack2(v2, v3);
                    short* dst = (g < 2)
                        ? (Qt + ((size_t)b * N + n) * QKD + (ofr & 15))
                        : (Kt + ((size_t)b * N + n) * QKD + (ofr & 15));
                    *(uint2*)dst = d;
                }
            } else {
                int c0 = o_base - 32;          // 0, 32, 64
                // permuted V column: swap key-quads 1<->2 within each 16-group
                int np = (n & ~12) | ((n & 4) << 1) | ((n & 8) >> 1);
                short* vb = Vw + ((size_t)b * PD + c0) * N + np;
                #pragma unroll
                for (int r = 0; r < 16; r++) {
                    int cf = (r & 3) + 8 * (r >> 2) + 4 * hi;
                    vb[(size_t)cf * N] = (short)f2bf(a[r] + qbl[32 + c0 + cf]);
                }
            }
        }
    }
}

// ---------------------------------------- K3: MFMA flash attention, LDS-staged V
// grid (B, 8), 256 threads = 4 waves, each wave owns 32 queries; full
// 1024-key loop (NO key-split: half the LDS -> 27.6 KB -> 5 blocks/CU =
// 20 waves/CU vs 16 before; barrier couples 4 waves not 8; combine
// epilogue eliminated). V staged via LDS double-buffer, T14
// issue-early/write-late. V columns pre-permuted (k_qkv) so P B-fragments
// are built LANE-LOCALLY: pb0 = pw[0..3], pb1 = pw[4..7] -- no shuffles.
__global__ __launch_bounds__(256, 4) void k_attn(const short* __restrict__ Qt,
                                                 const short* __restrict__ Kt,
                                                 const short* __restrict__ Vb,
                                                 short* __restrict__ y1t) {
    alignas(16) __shared__ char lds_raw[2 * 96 * VST * 2];  // 27648 B
    short* Vs = (short*)lds_raw;   // [buf][96*VST]

    int b = blockIdx.x;
    int tid = threadIdx.x;
    int w = tid >> 6, lane = tid & 63;
    int col = lane & 31, hi = lane >> 5;
    int q0 = blockIdx.y * 128 + w * 32;

    const short* kbase = Kt + (size_t)b * N * QKD;
    const short* vbase = Vb + (size_t)b * PD * N;
    const bf16x8 qf = *(const bf16x8*)(Qt + ((size_t)b * N + q0 + col) * QKD + hi * 8);

    short* vs0 = Vs;
    short* vs1 = Vs + 96 * VST;

    bf16x8 kf0 = *(const bf16x8*)(kbase + (size_t)(col) * QKD + hi * 8);
    bf16x8 kf1 = *(const bf16x8*)(kbase + (size_t)(32 + col) * QKD + hi * 8);
    {
        int t0 = tid, t1 = tid + 256, t2i = tid + 512;
        uint4 g0 = *(const uint4*)(vbase + (size_t)(t0 >> 3) * N + (t0 & 7) * 8);
        uint4 g1 = *(const uint4*)(vbase + (size_t)(t1 >> 3) * N + (t1 & 7) * 8);
        uint4 g2 = *(const uint4*)(vbase + (size_t)(t2i >> 3) * N + (t2i & 7) * 8);
        *(uint4*)(vs0 + (t0 >> 3) * VST + (t0 & 7) * 8) = g0;
        *(uint4*)(vs0 + (t1 >> 3) * VST + (t1 & 7) * 8) = g1;
        *(uint4*)(vs0 + (t2i >> 3) * VST + (t2i & 7) * 8) = g2;
    }
    __syncthreads();

    f32x16 acc0 = zero16(), acc1 = zero16(), acc2 = zero16();
    float m = -1e30f, lsum = 0.f;

    for (int it = 0; it < 16; it++) {
        int m0 = it * 64;
        short* cur = (it & 1) ? vs1 : vs0;
        short* nxt = (it & 1) ? vs0 : vs1;
        bool more = (it < 15);
        int m0n = more ? m0 + 64 : m0;
        bf16x8 kf0n = *(const bf16x8*)(kbase + (size_t)(m0n + col) * QKD + hi * 8);
        bf16x8 kf1n = *(const bf16x8*)(kbase + (size_t)(m0n + 32 + col) * QKD + hi * 8);
        uint4 g0, g1, g2;
        if (more) {
            int t0 = tid, t1 = tid + 256, t2i = tid + 512;
            g0 = *(const uint4*)(vbase + (size_t)(t0 >> 3) * N + m0n + (t0 & 7) * 8);
            g1 = *(const uint4*)(vbase + (size_t)(t1 >> 3) * N + m0n + (t1 & 7) * 8);
            g2 = *(const uint4*)(vbase + (size_t)(t2i >> 3) * N + m0n + (t2i & 7) * 8);
        }

        f32x16 s0 = MFMA(kf0, qf, zero16());
        f32x16 s1 = MFMA(kf1, qf, zero16());
        float a0 = max3f(s0[0], s0[1], s0[2]),  a1 = max3f(s0[3], s0[4], s0[5]);
        float a2 = max3f(s0[6], s0[7], s0[8]),  a3 = max3f(s0[9], s0[10], s0[11]);
        float a4 = max3f(s0[12], s0[13], s0[14]);
        float cm0 = fmaxf(max3f(a0, a1, a2), max3f(a3, a4, s0[15]));
        float b0_ = max3f(s1[0], s1[1], s1[2]),  b1_ = max3f(s1[3], s1[4], s1[5]);
        float b2_ = max3f(s1[6], s1[7], s1[8]),  b3_ = max3f(s1[9], s1[10], s1[11]);
        float b4_ = max3f(s1[12], s1[13], s1[14]);
        float cm1 = fmaxf(max3f(b0_, b1_, b2_), max3f(b3_, b4_, s1[15]));
        float cm = fmaxf(cm0, cm1);
        cm = fmaxf(cm, __shfl_xor(cm, 32, 64));
        if (!__all(cm <= m + 8.f)) {       // defer-max (T13), once per 64 keys
            float mnew = fmaxf(m, cm);
            float corr = __builtin_amdgcn_exp2f(m - mnew);
            m = mnew;
            lsum *= corr;
            #pragma unroll
            for (int r = 0; r < 16; r++) { acc0[r] *= corr; acc1[r] *= corr; acc2[r] *= corr; }
        }
        // exponentiate; fragments are lane-local thanks to the V permutation
        float ps = 0.f;
        bf16x8 pbv[2][2];
        #pragma unroll
        for (int s32 = 0; s32 < 2; s32++) {
            const f32x16& s = s32 ? s1 : s0;
            unsigned pw[8];
            #pragma unroll
            for (int j = 0; j < 8; j++) {
                float p0 = __builtin_amdgcn_exp2f(s[2 * j] - m);
                float p1 = __builtin_amdgcn_exp2f(s[2 * j + 1] - m);
                ps += p0 + p1;
                pw[j] = cvtpk(p0, p1);
            }
            union { unsigned u[4]; bf16x8 v; } pb0, pb1;
            pb0.u[0] = pw[0]; pb0.u[1] = pw[1]; pb0.u[2] = pw[2]; pb0.u[3] = pw[3];
            pb1.u[0] = pw[4]; pb1.u[1] = pw[5]; pb1.u[2] = pw[6]; pb1.u[3] = pw[7];
            pbv[s32][0] = pb0.v;
            pbv[s32][1] = pb1.v;
        }
        ps += __shfl_xor(ps, 32, 64);
        lsum += ps;
        __builtin_amdgcn_s_setprio(1);
        #pragma unroll
        for (int s32 = 0; s32 < 2; s32++) {
            const short* vt32 = cur + s32 * 32 + hi * 8;
            bf16x8 pa = pbv[s32][0], pq = pbv[s32][1];
            bf16x8 va0 = *(const bf16x8*)(vt32 + col * VST);
            bf16x8 va1 = *(const bf16x8*)(vt32 + col * VST + 16);
            acc0 = MFMA(va0, pa, acc0);
            acc0 = MFMA(va1, pq, acc0);
            bf16x8 vb0 = *(const bf16x8*)(vt32 + (32 + col) * VST);
            bf16x8 vb1 = *(const bf16x8*)(vt32 + (32 + col) * VST + 16);
            acc1 = MFMA(vb0, pa, acc1);
            acc1 = MFMA(vb1, pq, acc1);
            bf16x8 vc0 = *(const bf16x8*)(vt32 + (64 + col) * VST);
            bf16x8 vc1 = *(const bf16x8*)(vt32 + (64 + col) * VST + 16);
            acc2 = MFMA(vc0, pa, acc2);
            acc2 = MFMA(vc1, pq, acc2);
        }
        __builtin_amdgcn_s_setprio(0);
        kf0 = kf0n; kf1 = kf1n;
        if (more) {
            int t0 = tid, t1 = tid + 256, t2i = tid + 512;
            *(uint4*)(nxt + (t0 >> 3) * VST + (t0 & 7) * 8) = g0;
            *(uint4*)(nxt + (t1 >> 3) * VST + (t1 & 7) * 8) = g1;
            *(uint4*)(nxt + (t2i >> 3) * VST + (t2i & 7) * 8) = g2;
            __syncthreads();
        }
    }

    // direct epilogue (no split combine)
    float inv = 1.f / lsum;
    short* yrow = y1t + ((size_t)b * N + q0 + col) * PD;
    #pragma unroll
    for (int cg = 0; cg < 3; cg++) {
        f32x16 a = (cg == 0) ? acc0 : ((cg == 1) ? acc1 : acc2);
        #pragma unroll
        for (int j = 0; j < 8; j++) {
            float v0 = a[2 * j] * inv, v1 = a[2 * j + 1] * inv;
            v0 = v0 / (1.f + __expf(-v0));   // silu
            v1 = v1 / (1.f + __expf(-v1));
            int c = cg * 32 + ((2 * j) & 3) + 8 * (j >> 1) + 4 * hi;
            *(unsigned*)(yrow + c) = pack2(v0, v1);
        }
    }
}

// ---------------- K4: y2t[b][n][c-96] = bf16(silu(x[b][c][n])) (float4 reads)
__global__ __launch_bounds__(256) void k_trans(const float* __restrict__ x,
                                               short* __restrict__ y2t) {
    int b = blockIdx.x, ct = blockIdx.y, nt = blockIdx.z;
    int tid = threadIdx.x;
    __shared__ short t[32][132];
    int c0 = PD + ct * 32, n0 = nt * 128;
    const float* xb = x + ((size_t)b * DIM + c0) * N + n0;
    #pragma unroll
    for (int i = 0; i < 4; i++) {
        int e = tid + 256 * i;
        int c = e >> 5, q4 = e & 31;
        float4 v = *(const float4*)(xb + (size_t)c * N + q4 * 4);
        float s0 = v.x / (1.f + __expf(-v.x));
        float s1 = v.y / (1.f + __expf(-v.y));
        float s2 = v.z / (1.f + __expf(-v.z));
        float s3 = v.w / (1.f + __expf(-v.w));
        uint2 d;
        d.x = pack2(s0, s1);
        d.y = pack2(s2, s3);
        *(uint2*)&t[c][q4 * 4] = d;
    }
    __syncthreads();
    #pragma unroll
    for (int i = 0; i < 8; i++) {
        int e = tid + 256 * i;
        int n = e >> 4, cp = e & 15;
        unsigned lo = (unsigned short)t[2 * cp][n];
        unsigned hi = (unsigned short)t[2 * cp + 1][n];
        *(unsigned*)(y2t + ((size_t)b * N + n0 + n) * Y2C + ct * 32 + 2 * cp) = lo | (hi << 16);
    }
}

// ---------------- K5: out = W' @ [y1t; y2t] + bias
// LDS-staged MFMA GEMM (m97 structure): 128o x 128n tile, BK=32, 4 waves.
__global__ __launch_bounds__(256) void k_proj(const short* __restrict__ Wp,
                                              const short* __restrict__ y1t,
                                              const short* __restrict__ y2t,
                                              const float* __restrict__ bias,
                                              float* __restrict__ out) {
    __shared__ short Asl[128 * 32];
    __shared__ short Bsl[128 * 32];
    int b = blockIdx.x, ob = blockIdx.y, nb = blockIdx.z;
    int tid = threadIdx.x, w = tid >> 6, l = tid & 63;
    int col = l & 31, hi = l >> 5;
    int wr = w >> 1, wc = w & 1;
    int o0 = ob * 128, n0 = nb * 128;
    size_t bn = (size_t)b * N + n0;

    f32x16 acc[2][2];
    acc[0][0] = zero16(); acc[0][1] = zero16();
    acc[1][0] = zero16(); acc[1][1] = zero16();

    int srow = (l >> 2);        // 0..15 within a 16-row issue
    int sslotbase = (l & 3);    // 16B slot within 64B row

    for (int step = 0; step < 12; step++) {
        int k0 = step * 32;
        const short* ysrc;
        int ystride, kq;
        if (k0 < PD) { ysrc = y1t; ystride = PD;  kq = k0; }
        else         { ysrc = y2t; ystride = Y2C; kq = k0 - PD; }
        #pragma unroll
        for (int i = 0; i < 2; i++) {
            int row = w * 32 + i * 16 + srow;
            int sl = sslotbase ^ (row & 3);
            GLOAD16(Wp + (size_t)(o0 + row) * DIM + k0 + sl * 8,
                    &Asl[(w * 32 + i * 16) * 32]);
            GLOAD16(ysrc + (bn + row) * ystride + kq + sl * 8,
                    &Bsl[(w * 32 + i * 16) * 32]);
        }
        __syncthreads();
        #pragma unroll
        for (int kh = 0; kh < 2; kh++) {
            int bxor = ((kh << 5) + (hi << 4));
            int ra0 = wr * 64 + col,      ra1 = ra0 + 32;
            int rb0 = wc * 64 + col,      rb1 = rb0 + 32;
            bf16x8 a0 = *(const bf16x8*)&Asl[ra0 * 32 + ((bxor ^ ((ra0 & 3) << 4)) >> 1)];
            bf16x8 a1 = *(const bf16x8*)&Asl[ra1 * 32 + ((bxor ^ ((ra1 & 3) << 4)) >> 1)];
            bf16x8 b0 = *(const bf16x8*)&Bsl[rb0 * 32 + ((bxor ^ ((rb0 & 3) << 4)) >> 1)];
            bf16x8 b1 = *(const bf16x8*)&Bsl[rb1 * 32 + ((bxor ^ ((rb1 & 3) << 4)) >> 1)];
            acc[0][0] = MFMA(a0, b0, acc[0][0]);
            acc[0][1] = MFMA(a0, b1, acc[0][1]);
            acc[1][0] = MFMA(a1, b0, acc[1][0]);
            acc[1][1] = MFMA(a1, b1, acc[1][1]);
        }
        __syncthreads();
    }
    #pragma unroll
    for (int m = 0; m < 2; m++) {
        #pragma unroll
        for (int n = 0; n < 2; n++) {
            #pragma unroll
            for (int r = 0; r < 16; r++) {
                int o = o0 + wr * 64 + m * 32 + (r & 3) + 8 * (r >> 2) + 4 * hi;
                out[((size_t)b * DIM + o) * N + n0 + wc * 64 + n * 32 + col] =
                    acc[m][n][r] + bias[o];
            }
        }
    }
}

// -----------------------------------------------------------------------------
// ws layout (~50.7 MB): y2t (37.75 MB) aliases [Qt,Kt,Vw]+tail (dead after
// k_attn; k_trans runs after k_attn on the same stream; rewritten every call).
extern "C" void kernel_launch(void* const* d_in, const int* in_sizes, int n_in,
                              void* d_out, int out_size, void* d_ws, size_t ws_size,
                              hipStream_t stream) {
    const float* x    = (const float*)d_in[0];
    const float* gnw  = (const float*)d_in[1];
    const float* gnb  = (const float*)d_in[2];
    const float* qkvw = (const float*)d_in[3];
    const float* qbnw = (const float*)d_in[4];
    const float* qbnb = (const float*)d_in[5];
    const float* qbnm = (const float*)d_in[6];
    const float* qbnv = (const float*)d_in[7];
    const float* pw   = (const float*)d_in[8];
    const float* pbnw = (const float*)d_in[9];
    const float* pbnb = (const float*)d_in[10];
    const float* pbnm = (const float*)d_in[11];
    const float* pbnv = (const float*)d_in[12];
    float* out = (float*)d_out;

    char* p = (char*)d_ws;
    float* part  = (float*)p;  p += 4096;                      // 64*8*2 floats
    short* Wp    = (short*)p;  p += (size_t)DIM * DIM * 2;     // 288 KB
    float* bias  = (float*)p;  p += 1536;                      // DIM*4
    short* Wq    = (short*)p;  p += (size_t)OQ * PD * 2;       // 24 KB
    float* qbias = (float*)p;  p += 512;                       // OQ*4
    short* y1t   = (short*)p;  p += (size_t)B * N * PD * 2;    // 12.6 MB
    short* Qt    = (short*)p;                                  // 2 MB   (dead after attn)
    short* Kt    = Qt + (size_t)B * N * QKD;                   // 2 MB   (dead after attn)
    short* Vw    = Kt + (size_t)B * N * QKD;                   // 12.6 MB(dead after attn)
    short* y2t   = Qt;                                         // 37.75 MB alias

    k_pre<<<1136, 256, 0, stream>>>(x, part, pw, pbnw, pbnb, pbnm, pbnv, Wp, bias,
                                    qkvw, qbnw, qbnb, qbnm, qbnv, Wq, qbias);
    k_qkv<<<dim3(B, 8), 256, 0, stream>>>(x, part, gnw, gnb, Wq, qbias, Qt, Kt, Vw);
    k_attn<<<dim3(B, 8), 256, 0, stream>>>(Qt, Kt, Vw, y1t);
    k_trans<<<dim3(B, 9, 8), 256, 0, stream>>>(x, y2t);
    k_proj<<<dim3(B, 3, 8), 256, 0, stream>>>(Wp, y1t, y2t, bias, out);
}